// Round 1
// baseline (9074.870 us; speedup 1.0000x reference)
//
#include <hip/hip_runtime.h>
#include <cstdint>
#include <cstddef>

#define CI_TILE 8

// ---------------- conv 3x3 SAME, C=256 -> C=256, +bias, optional relu -------
// grid: (tilesX*tilesY, 16 co-groups, N). block 256 = 16x16 spatial tile.
// Each thread accumulates 16 consecutive output channels for one pixel.
__global__ __launch_bounds__(256) void conv3x3_k(
    const float* __restrict__ in, const float* __restrict__ w,
    const float* __restrict__ b, float* __restrict__ out,
    int H, int W, int relu)
{
    const int tid = threadIdx.x;
    const int tx = tid & 15, ty = tid >> 4;
    const int tilesX = (W + 15) >> 4;
    const int bx = blockIdx.x % tilesX, by = blockIdx.x / tilesX;
    const int x0 = bx << 4, y0 = by << 4;
    const int n = blockIdx.z;
    const int so = blockIdx.y << 4;
    const int HWl = H * W;

    __shared__ float patch[CI_TILE][18 * 18];

    float acc[16];
#pragma unroll
    for (int j = 0; j < 16; ++j) acc[j] = 0.f;

    const float* inp = in + (size_t)n * 256 * HWl;
    const int x = x0 + tx, y = y0 + ty;

    for (int cb = 0; cb < 256; cb += CI_TILE) {
        __syncthreads();
        for (int idx = tid; idx < CI_TILE * 324; idx += 256) {
            int ci = idx / 324, p = idx - ci * 324;
            int py = p / 18, px = p - py * 18;
            int gy = y0 + py - 1, gx = x0 + px - 1;
            float v = 0.f;
            if (gy >= 0 && gy < H && gx >= 0 && gx < W)
                v = inp[(size_t)(cb + ci) * HWl + (size_t)gy * W + gx];
            patch[ci][p] = v;
        }
        __syncthreads();
        const float* wp = w + ((size_t)so * 256 + cb) * 9;
        for (int ci = 0; ci < CI_TILE; ++ci) {
            float v[9];
#pragma unroll
            for (int t = 0; t < 9; ++t)
                v[t] = patch[ci][(ty + t / 3) * 18 + tx + (t % 3)];
#pragma unroll
            for (int j = 0; j < 16; ++j) {
#pragma unroll
                for (int t = 0; t < 9; ++t)
                    acc[j] = fmaf(wp[(j * 256 + ci) * 9 + t], v[t], acc[j]);
            }
        }
    }
    if (x < W && y < H) {
        size_t base = (size_t)n * 256 * HWl + (size_t)y * W + x;
#pragma unroll
        for (int j = 0; j < 16; ++j) {
            float r = acc[j] + b[so + j];
            if (relu) r = fmaxf(r, 0.f);
            out[base + (size_t)(so + j) * HWl] = r;
        }
    }
}

// ---------------- p-branch 1x1 heads: p_log(3), p_del(12), cell scores ------
__global__ __launch_bounds__(256) void p_heads_k(
    const float* __restrict__ hid, const float* __restrict__ plw,
    const float* __restrict__ plb, const float* __restrict__ pdw,
    const float* __restrict__ pdb, float* __restrict__ out_plog,
    float* __restrict__ out_pdel, float* __restrict__ scores, int HW)
{
    int s = blockIdx.x * 256 + threadIdx.x;
    int n = blockIdx.y;
    if (s >= HW) return;
    const float* hp = hid + (size_t)n * 256 * HW + s;
    float acc[15];
#pragma unroll
    for (int a = 0; a < 15; ++a) acc[a] = 0.f;
    for (int c = 0; c < 256; ++c) {
        float v = hp[(size_t)c * HW];
#pragma unroll
        for (int a = 0; a < 3; ++a)  acc[a]     = fmaf(plw[a * 256 + c], v, acc[a]);
#pragma unroll
        for (int a = 0; a < 12; ++a) acc[3 + a] = fmaf(pdw[a * 256 + c], v, acc[3 + a]);
    }
    float sc = -INFINITY;
#pragma unroll
    for (int a = 0; a < 3; ++a) {
        float lg = acc[a] + plb[a];
        out_plog[((size_t)n * 3 + a) * HW + s] = lg;
        sc = fmaxf(sc, lg);
    }
    scores[(size_t)n * HW + s] = sc;
#pragma unroll
    for (int a = 0; a < 12; ++a)
        out_pdel[((size_t)n * 12 + a) * HW + s] = acc[3 + a] + pdb[a];
}

// ---------------- o-branch 1x1 head: o_del(12) -----------------------------
__global__ __launch_bounds__(256) void o_del_k(
    const float* __restrict__ y, const float* __restrict__ odw,
    const float* __restrict__ odb, float* __restrict__ out_odel, int HW)
{
    int s = blockIdx.x * 256 + threadIdx.x;
    int n = blockIdx.y;
    if (s >= HW) return;
    const float* yp = y + (size_t)n * 256 * HW + s;
    float acc[12];
#pragma unroll
    for (int a = 0; a < 12; ++a) acc[a] = 0.f;
    for (int c = 0; c < 256; ++c) {
        float v = yp[(size_t)c * HW];
#pragma unroll
        for (int a = 0; a < 12; ++a) acc[a] = fmaf(odw[a * 256 + c], v, acc[a]);
    }
#pragma unroll
    for (int a = 0; a < 12; ++a)
        out_odel[((size_t)n * 12 + a) * HW + s] = acc[a] + odb[a];
}

// ---------------- per-level top-20 (value desc, tie -> lower index) ---------
__global__ __launch_bounds__(256) void topk_level_k(
    const float* __restrict__ scores, float* __restrict__ lv_sc,
    int* __restrict__ lv_ix, int4 hws, int4 soffs)
{
    int l = blockIdx.x, n = blockIdx.y;
    int HW = (l == 0) ? hws.x : (l == 1) ? hws.y : (l == 2) ? hws.z : hws.w;
    int so = (l == 0) ? soffs.x : (l == 1) ? soffs.y : (l == 2) ? soffs.z : soffs.w;
    __shared__ float sc[10240];
    __shared__ float rv[256];
    __shared__ int   ri[256];
    int tid = threadIdx.x;
    for (int i = tid; i < HW; i += 256) sc[i] = scores[so + (size_t)n * HW + i];
    __syncthreads();
    for (int r = 0; r < 20; ++r) {
        float bv = -INFINITY; int bi = 0x7fffffff;
        for (int i = tid; i < HW; i += 256) {
            float v = sc[i];
            if (v > bv || (v == bv && i < bi)) { bv = v; bi = i; }
        }
        rv[tid] = bv; ri[tid] = bi;
        __syncthreads();
        for (int off = 128; off > 0; off >>= 1) {
            if (tid < off) {
                float v2 = rv[tid + off]; int i2 = ri[tid + off];
                if (v2 > rv[tid] || (v2 == rv[tid] && i2 < ri[tid])) {
                    rv[tid] = v2; ri[tid] = i2;
                }
            }
            __syncthreads();
        }
        if (tid == 0) {
            int idx = (n * 4 + l) * 20 + r;
            lv_sc[idx] = rv[0];
            lv_ix[idx] = ri[0];
            sc[ri[0]] = -INFINITY;
        }
        __syncthreads();
    }
}

// ---------------- global top-20 of 80 + gather pf ---------------------------
__global__ __launch_bounds__(256) void select_gather_k(
    const float* __restrict__ lv_sc, const int* __restrict__ lv_ix,
    const float* __restrict__ hid, float* __restrict__ pf,
    int4 hws, int4 hoffs)
{
    int n = blockIdx.x;
    __shared__ float gsc[80];
    __shared__ int   gcell[80];
    __shared__ int   selL[20], selC[20];
    __shared__ float rv[256];
    __shared__ int   ri[256];
    int tid = threadIdx.x;
    if (tid < 80) {
        gsc[tid] = lv_sc[n * 80 + tid];
        gcell[tid] = lv_ix[n * 80 + tid];
    }
    __syncthreads();
    for (int r = 0; r < 20; ++r) {
        float bv = -INFINITY; int bi = 0x7fffffff;
        if (tid < 80) { bv = gsc[tid]; bi = tid; }
        rv[tid] = bv; ri[tid] = bi;
        __syncthreads();
        for (int off = 128; off > 0; off >>= 1) {
            if (tid < off) {
                float v2 = rv[tid + off]; int i2 = ri[tid + off];
                if (v2 > rv[tid] || (v2 == rv[tid] && i2 < ri[tid])) {
                    rv[tid] = v2; ri[tid] = i2;
                }
            }
            __syncthreads();
        }
        if (tid == 0) {
            int j = ri[0];
            selL[r] = j / 20;
            selC[r] = gcell[j];
            gsc[j] = -INFINITY;
        }
        __syncthreads();
    }
    for (int t = tid; t < 20 * 256; t += 256) {
        int k = t >> 8, c = t & 255;
        int l = selL[k], cell = selC[k];
        int HW = (l == 0) ? hws.x : (l == 1) ? hws.y : (l == 2) ? hws.z : hws.w;
        int ho = (l == 0) ? hoffs.x : (l == 1) ? hoffs.y : (l == 2) ? hoffs.z : hoffs.w;
        pf[((size_t)n * 20 + k) * 256 + c] =
            hid[(size_t)ho + ((size_t)n * 256 + c) * HW + cell];
    }
}

// ---------------- p_proj = pf @ Wp^T + rn1_b --------------------------------
__global__ __launch_bounds__(256) void pproj_k(
    const float* __restrict__ pf, const float* __restrict__ WpT,
    const float* __restrict__ rn1b, float* __restrict__ pp)
{
    int nk = blockIdx.x;        // 0..39 (n*20+k)
    int t = threadIdx.x;
    __shared__ float f[256];
    f[t] = pf[(size_t)nk * 256 + t];
    __syncthreads();
    float acc = rn1b[t];
    for (int c = 0; c < 256; ++c) acc = fmaf(f[c], WpT[c * 256 + t], acc);
    pp[(size_t)nk * 256 + t] = acc;
}

// ---------------- fused o_proj + sum_k relu(o_proj + p_proj) ----------------
// grid: (ceil(HW/64), N). tile = 64 s x 256 d. thread: 4 d x 16 s.
__global__ __launch_bounds__(256) void oproj_hsum_k(
    const float* __restrict__ y, const float* __restrict__ WoT,
    const float* __restrict__ pp, float* __restrict__ hsum, int HW)
{
    int n = blockIdx.y;
    int s0 = blockIdx.x * 64;
    int tid = threadIdx.x;
    int dq = tid & 63, sg = tid >> 6;

    __shared__ float ylds[32][64];
    __shared__ float pplds[20 * 256];

    for (int i = tid; i < 20 * 256; i += 256) pplds[i] = pp[(size_t)n * 20 * 256 + i];

    const float* yb = y + (size_t)n * 256 * HW;
    float acc[4][16];
#pragma unroll
    for (int i = 0; i < 4; ++i)
#pragma unroll
        for (int j = 0; j < 16; ++j) acc[i][j] = 0.f;

    for (int cb = 0; cb < 256; cb += 32) {
        __syncthreads();
        for (int idx = tid; idx < 32 * 64; idx += 256) {
            int i = idx >> 6, j = idx & 63;
            int s = s0 + j;
            ylds[i][j] = (s < HW) ? yb[(size_t)(cb + i) * HW + s] : 0.f;
        }
        __syncthreads();
#pragma unroll 4
        for (int i = 0; i < 32; ++i) {
            float4 w4 = *(const float4*)&WoT[(size_t)(cb + i) * 256 + dq * 4];
            const float* yr = &ylds[i][sg * 16];
#pragma unroll
            for (int j = 0; j < 16; ++j) {
                float yv = yr[j];
                acc[0][j] = fmaf(w4.x, yv, acc[0][j]);
                acc[1][j] = fmaf(w4.y, yv, acc[1][j]);
                acc[2][j] = fmaf(w4.z, yv, acc[2][j]);
                acc[3][j] = fmaf(w4.w, yv, acc[3][j]);
            }
        }
    }
#pragma unroll
    for (int i = 0; i < 4; ++i) {
        int d = dq * 4 + i;
        float pk[20];
#pragma unroll
        for (int k = 0; k < 20; ++k) pk[k] = pplds[k * 256 + d];
#pragma unroll
        for (int j = 0; j < 16; ++j) {
            float v = acc[i][j];
            float h = 0.f;
#pragma unroll
            for (int k = 0; k < 20; ++k) h += fmaxf(v + pk[k], 0.f);
            acc[i][j] = h;
        }
    }
#pragma unroll
    for (int j = 0; j < 16; ++j) {
        int s = s0 + sg * 16 + j;
        if (s < HW) {
            float4 o = make_float4(acc[0][j], acc[1][j], acc[2][j], acc[3][j]);
            *(float4*)&hsum[((size_t)n * HW + s) * 256 + dq * 4] = o;
        }
    }
}

// ---------------- rn2 GEMM + relu + ol head, per 16-s tile ------------------
// grid: (HW/16, N). thread: 4 d x 4 s.
__global__ __launch_bounds__(256) void rn2_ol_k(
    const float* __restrict__ hsum, const float* __restrict__ rn2T,
    const float* __restrict__ rn2b, const float* __restrict__ olw,
    const float* __restrict__ olb, float* __restrict__ out_olog, int HW)
{
    int n = blockIdx.y;
    int s0 = blockIdx.x * 16;
    int tid = threadIdx.x;
    int dq = tid & 63, sg = tid >> 6;

    __shared__ float hsT[256 * 16];     // [e][s]
    __shared__ float h2L[16][257];

    const float* hb = hsum + ((size_t)n * HW + s0) * 256;
#pragma unroll
    for (int i = 0; i < 16; ++i) hsT[tid * 16 + i] = hb[(size_t)i * 256 + tid];
    __syncthreads();

    float acc[4][4];
#pragma unroll
    for (int i = 0; i < 4; ++i)
#pragma unroll
        for (int j = 0; j < 4; ++j) acc[i][j] = 0.f;

    for (int kk = 0; kk < 256; ++kk) {
        float4 w4 = *(const float4*)&rn2T[(size_t)kk * 256 + dq * 4];
        float4 h4 = *(const float4*)&hsT[kk * 16 + sg * 4];
        acc[0][0] = fmaf(w4.x, h4.x, acc[0][0]); acc[0][1] = fmaf(w4.x, h4.y, acc[0][1]);
        acc[0][2] = fmaf(w4.x, h4.z, acc[0][2]); acc[0][3] = fmaf(w4.x, h4.w, acc[0][3]);
        acc[1][0] = fmaf(w4.y, h4.x, acc[1][0]); acc[1][1] = fmaf(w4.y, h4.y, acc[1][1]);
        acc[1][2] = fmaf(w4.y, h4.z, acc[1][2]); acc[1][3] = fmaf(w4.y, h4.w, acc[1][3]);
        acc[2][0] = fmaf(w4.z, h4.x, acc[2][0]); acc[2][1] = fmaf(w4.z, h4.y, acc[2][1]);
        acc[2][2] = fmaf(w4.z, h4.z, acc[2][2]); acc[2][3] = fmaf(w4.z, h4.w, acc[2][3]);
        acc[3][0] = fmaf(w4.w, h4.x, acc[3][0]); acc[3][1] = fmaf(w4.w, h4.y, acc[3][1]);
        acc[3][2] = fmaf(w4.w, h4.z, acc[3][2]); acc[3][3] = fmaf(w4.w, h4.w, acc[3][3]);
    }
#pragma unroll
    for (int i = 0; i < 4; ++i) {
        float bb = rn2b[dq * 4 + i];
#pragma unroll
        for (int j = 0; j < 4; ++j)
            h2L[sg * 4 + j][dq * 4 + i] = fmaxf(acc[i][j] + bb, 0.f);
    }
    __syncthreads();
    if (tid < 48) {
        int s = tid / 3, a = tid - (tid / 3) * 3;
        float acc2 = olb[a];
        for (int d = 0; d < 256; ++d) acc2 = fmaf(olw[a * 256 + d], h2L[s][d], acc2);
        out_olog[((size_t)n * 3 + a) * HW + s0 + s] = acc2;
    }
}

// ---------------- weight transposes ----------------------------------------
__global__ __launch_bounds__(256) void prep_w_k(
    const float* __restrict__ rn1w, const float* __restrict__ rn2w,
    float* __restrict__ WoT, float* __restrict__ WpT, float* __restrict__ rn2T)
{
    int d = blockIdx.x;
    int c = threadIdx.x;
    WoT[c * 256 + d] = rn1w[(size_t)d * 512 + c];
    WpT[c * 256 + d] = rn1w[(size_t)d * 512 + 256 + c];
    rn2T[c * 256 + d] = rn2w[(size_t)d * 256 + c];
}

extern "C" void kernel_launch(void* const* d_in, const int* in_sizes, int n_in,
                              void* d_out, int out_size, void* d_ws, size_t ws_size,
                              hipStream_t stream)
{
    const float* feat[4] = {(const float*)d_in[0], (const float*)d_in[1],
                            (const float*)d_in[2], (const float*)d_in[3]};
    const float* pc1w = (const float*)d_in[4];  const float* pc1b = (const float*)d_in[5];
    const float* pc2w = (const float*)d_in[6];  const float* pc2b = (const float*)d_in[7];
    const float* oc1w = (const float*)d_in[8];  const float* oc1b = (const float*)d_in[9];
    const float* oc2w = (const float*)d_in[10]; const float* oc2b = (const float*)d_in[11];
    const float* rn1w = (const float*)d_in[12]; const float* rn1b = (const float*)d_in[13];
    const float* rn2w = (const float*)d_in[14]; const float* rn2b = (const float*)d_in[15];
    const float* plw  = (const float*)d_in[16]; const float* plb  = (const float*)d_in[17];
    const float* pdw  = (const float*)d_in[18]; const float* pdb  = (const float*)d_in[19];
    const float* olw  = (const float*)d_in[20]; const float* olb  = (const float*)d_in[21];
    const float* odw  = (const float*)d_in[22]; const float* odb  = (const float*)d_in[23];

    float* ws = (float*)d_ws;
    float* big0   = ws;                    // 6,963,200 : p_hid all levels / o-branch y
    float* big1   = ws + 6963200;          // 5,242,880 : conv tmp / hsum
    float* scores = ws + 12206080;         // 27,200
    float* lv_sc  = ws + 12233280;         // 160
    int*   lv_ix  = (int*)(ws + 12233440); // 160
    float* pf     = ws + 12233600;         // 10,240
    float* pp     = ws + 12243840;         // 10,240
    float* WoT    = ws + 12254080;         // 65,536
    float* WpT    = ws + 12319616;         // 65,536
    float* rn2T   = ws + 12385152;         // 65,536

    const int Hs[4] = {80, 40, 20, 10}, Wsz[4] = {128, 64, 32, 16};
    const int HWs[4] = {10240, 2560, 640, 160};
    const size_t hoff[4] = {0, 5242880, 6553600, 6881280};
    const int soff[4] = {0, 20480, 25600, 26880};
    float* out = (float*)d_out;
    const size_t plog_off[4] = {0, 61440, 76800, 80640};
    const size_t pdel_off[4] = {81600, 327360, 388800, 404160};
    const size_t olog_off[4] = {408000, 469440, 484800, 488640};
    const size_t odel_off[4] = {489600, 735360, 796800, 812160};

    hipLaunchKernelGGL(prep_w_k, dim3(256), dim3(256), 0, stream,
                       rn1w, rn2w, WoT, WpT, rn2T);

    // ---------------- p-branch ----------------
    for (int l = 0; l < 4; ++l) {
        int H = Hs[l], W = Wsz[l], HW = HWs[l];
        dim3 gconv((unsigned)(((W + 15) / 16) * ((H + 15) / 16)), 16, 2);
        hipLaunchKernelGGL(conv3x3_k, gconv, dim3(256), 0, stream,
                           feat[l], pc1w, pc1b, big1, H, W, 1);
        hipLaunchKernelGGL(conv3x3_k, gconv, dim3(256), 0, stream,
                           big1, pc2w, pc2b, big0 + hoff[l], H, W, 1);
        dim3 gh((unsigned)((HW + 255) / 256), 2);
        hipLaunchKernelGGL(p_heads_k, gh, dim3(256), 0, stream,
                           big0 + hoff[l], plw, plb, pdw, pdb,
                           out + plog_off[l], out + pdel_off[l], scores + soff[l], HW);
    }

    hipLaunchKernelGGL(topk_level_k, dim3(4, 2), dim3(256), 0, stream,
                       scores, lv_sc, lv_ix,
                       make_int4(10240, 2560, 640, 160),
                       make_int4(0, 20480, 25600, 26880));
    hipLaunchKernelGGL(select_gather_k, dim3(2), dim3(256), 0, stream,
                       lv_sc, lv_ix, big0, pf,
                       make_int4(10240, 2560, 640, 160),
                       make_int4(0, 5242880, 6553600, 6881280));
    hipLaunchKernelGGL(pproj_k, dim3(40), dim3(256), 0, stream, pf, WpT, rn1b, pp);

    // ---------------- o-branch ----------------
    for (int l = 0; l < 4; ++l) {
        int H = Hs[l], W = Wsz[l], HW = HWs[l];
        dim3 gconv((unsigned)(((W + 15) / 16) * ((H + 15) / 16)), 16, 2);
        hipLaunchKernelGGL(conv3x3_k, gconv, dim3(256), 0, stream,
                           feat[l], oc1w, oc1b, big1, H, W, 1);
        hipLaunchKernelGGL(conv3x3_k, gconv, dim3(256), 0, stream,
                           big1, oc2w, oc2b, big0 + hoff[l], H, W, 1);
        dim3 gh((unsigned)((HW + 255) / 256), 2);
        hipLaunchKernelGGL(o_del_k, gh, dim3(256), 0, stream,
                           big0 + hoff[l], odw, odb, out + odel_off[l], HW);
        hipLaunchKernelGGL(oproj_hsum_k, dim3((unsigned)((HW + 63) / 64), 2), dim3(256), 0, stream,
                           big0 + hoff[l], WoT, pp, big1, HW);
        hipLaunchKernelGGL(rn2_ol_k, dim3((unsigned)(HW / 16), 2), dim3(256), 0, stream,
                           big1, rn2T, rn2b, olw, olb, out + olog_off[l], HW);
    }
}

// Round 2
// 3015.725 us; speedup vs baseline: 3.0092x; 3.0092x over previous
//
#include <hip/hip_runtime.h>
#include <cstdint>
#include <cstddef>

typedef __bf16 bf16x8 __attribute__((ext_vector_type(8)));
typedef float  f32x16 __attribute__((ext_vector_type(16)));

// ---------------- weight pre-transform: w[co][ci][3][3] fp32 -> wtap[t][co][ci] bf16
__global__ __launch_bounds__(256) void prep_wtap_k(const float* __restrict__ w,
                                                   __bf16* __restrict__ dst)
{
    int t = blockIdx.x, co = blockIdx.y, ci = threadIdx.x;
    dst[(size_t)((t << 8) + co) * 256 + ci] = (__bf16)w[(size_t)((co << 8) + ci) * 9 + t];
}

// ---------------- conv 3x3 SAME via implicit-GEMM MFMA (bf16 in, fp32 acc/out)
// block tile: 64 co x 256 spatial. 4 waves, each 64co x 64sp (2x2 frags of 32).
// K loop: ci chunks of 16 (one 32x32x16 MFMA k-step), 9 taps inner.
__global__ __launch_bounds__(256) void conv3x3_mfma_k(
    const float* __restrict__ in, const __bf16* __restrict__ wtap,
    const float* __restrict__ bias, float* __restrict__ out,
    int H, int W, int log2W, int HW, int relu)
{
    __shared__ __bf16 Asm[9][64][24];   // 27648 B, pitch 24 bf16 = 48 B (bank-uniform)
    __shared__ __bf16 Bsm[12480];       // 24960 B, halo [hp][ci16] pitch 24

    const int tid = threadIdx.x;
    const int n = blockIdx.z;
    const int cobase = blockIdx.y << 6;
    const int sp0 = blockIdx.x << 8;
    const int npix = min(256, HW - sp0);
    const int R = npix >> log2W;
    const int Hrows = R + 2, HC = W + 2;
    const int y0 = sp0 >> log2W;

    const int w = tid >> 6;
    const int l = tid & 63;
    const int lane = l & 31, half = l >> 5;

    const int pix0 = (w << 6) + lane;
    const int pix1 = pix0 + 32;
    const int py0 = pix0 >> log2W, px0 = pix0 & (W - 1);
    const int py1 = pix1 >> log2W, px1 = pix1 & (W - 1);
    const int hp0 = py0 * HC + px0;
    const int hp1 = py1 * HC + px1;

    const float* inb = in + (size_t)n * 256 * HW;
    float* outb = out + (size_t)n * 256 * HW;

    f32x16 acc00 = {}, acc01 = {}, acc10 = {}, acc11 = {};

    const int totB = Hrows * 8 * HC;

    for (int cb = 0; cb < 256; cb += 16) {
        __syncthreads();
        // stage A: 9 taps x 64 co x 16 ci, 8B vector copies (already bf16)
        for (int i = tid; i < 2304; i += 256) {
            int t = i >> 8;
            int r = i & 255;
            int co = r >> 2, q = r & 3;
            const ushort* src = (const ushort*)wtap +
                ((size_t)((t << 8) + cobase + co) << 8) + cb + (q << 2);
            *(ushort4*)((ushort*)&Asm[t][co][q << 2]) = *(const ushort4*)src;
        }
        // stage B: halo (R+2) x (W+2) x 16ci, fp32 -> bf16 pairs
        for (int i = tid; i < totB; i += 256) {
            int hx = i % HC;
            int rest = i / HC;
            int ciq = rest & 7;
            int hy = rest >> 3;
            int gy = y0 + hy - 1, gx = hx - 1;
            float v0 = 0.f, v1 = 0.f;
            if (gy >= 0 && gy < H && gx >= 0 && gx < W) {
                const float* s = inb + (size_t)(cb + (ciq << 1)) * HW + gy * W + gx;
                v0 = s[0]; v1 = s[HW];
            }
            union { __bf16 h[2]; unsigned u; } pk;
            pk.h[0] = (__bf16)v0; pk.h[1] = (__bf16)v1;
            *(unsigned*)((ushort*)&Bsm[(hy * HC + hx) * 24 + (ciq << 1)]) = pk.u;
        }
        __syncthreads();
#pragma unroll
        for (int dy = 0; dy < 3; ++dy) {
#pragma unroll
            for (int dx = 0; dx < 3; ++dx) {
                const int t = dy * 3 + dx;
                bf16x8 a0 = *(const bf16x8*)&Asm[t][lane][half << 3];
                bf16x8 a1 = *(const bf16x8*)&Asm[t][32 + lane][half << 3];
                bf16x8 b0 = *(const bf16x8*)&Bsm[(hp0 + dy * HC + dx) * 24 + (half << 3)];
                bf16x8 b1 = *(const bf16x8*)&Bsm[(hp1 + dy * HC + dx) * 24 + (half << 3)];
                acc00 = __builtin_amdgcn_mfma_f32_32x32x16_bf16(a0, b0, acc00, 0, 0, 0);
                acc01 = __builtin_amdgcn_mfma_f32_32x32x16_bf16(a0, b1, acc01, 0, 0, 0);
                acc10 = __builtin_amdgcn_mfma_f32_32x32x16_bf16(a1, b0, acc10, 0, 0, 0);
                acc11 = __builtin_amdgcn_mfma_f32_32x32x16_bf16(a1, b1, acc11, 0, 0, 0);
            }
        }
    }
    // epilogue: C/D layout col=lane&31 (pixel), row=(reg&3)+8*(reg>>2)+4*half (co)
    const int pixg0 = sp0 + pix0, pixg1 = sp0 + pix1;
    const bool ok0 = (pix0 < npix), ok1 = (pix1 < npix);
#pragma unroll
    for (int reg = 0; reg < 16; ++reg) {
        int rr = (reg & 3) + ((reg >> 2) << 3) + (half << 2);
        int co0 = cobase + rr;
        int co1 = co0 + 32;
        float b0v = bias[co0], b1v = bias[co1];
        if (ok0) {
            float r = acc00[reg] + b0v; if (relu) r = fmaxf(r, 0.f);
            outb[(size_t)co0 * HW + pixg0] = r;
            float r2 = acc10[reg] + b1v; if (relu) r2 = fmaxf(r2, 0.f);
            outb[(size_t)co1 * HW + pixg0] = r2;
        }
        if (ok1) {
            float r = acc01[reg] + b0v; if (relu) r = fmaxf(r, 0.f);
            outb[(size_t)co0 * HW + pixg1] = r;
            float r2 = acc11[reg] + b1v; if (relu) r2 = fmaxf(r2, 0.f);
            outb[(size_t)co1 * HW + pixg1] = r2;
        }
    }
}

// ---------------- p-branch 1x1 heads: p_log(3), p_del(12), cell scores ------
__global__ __launch_bounds__(256) void p_heads_k(
    const float* __restrict__ hid, const float* __restrict__ plw,
    const float* __restrict__ plb, const float* __restrict__ pdw,
    const float* __restrict__ pdb, float* __restrict__ out_plog,
    float* __restrict__ out_pdel, float* __restrict__ scores, int HW)
{
    int s = blockIdx.x * 256 + threadIdx.x;
    int n = blockIdx.y;
    if (s >= HW) return;
    const float* hp = hid + (size_t)n * 256 * HW + s;
    float acc[15];
#pragma unroll
    for (int a = 0; a < 15; ++a) acc[a] = 0.f;
    for (int c = 0; c < 256; ++c) {
        float v = hp[(size_t)c * HW];
#pragma unroll
        for (int a = 0; a < 3; ++a)  acc[a]     = fmaf(plw[a * 256 + c], v, acc[a]);
#pragma unroll
        for (int a = 0; a < 12; ++a) acc[3 + a] = fmaf(pdw[a * 256 + c], v, acc[3 + a]);
    }
    float sc = -INFINITY;
#pragma unroll
    for (int a = 0; a < 3; ++a) {
        float lg = acc[a] + plb[a];
        out_plog[((size_t)n * 3 + a) * HW + s] = lg;
        sc = fmaxf(sc, lg);
    }
    scores[(size_t)n * HW + s] = sc;
#pragma unroll
    for (int a = 0; a < 12; ++a)
        out_pdel[((size_t)n * 12 + a) * HW + s] = acc[3 + a] + pdb[a];
}

// ---------------- o-branch 1x1 head: o_del(12) -----------------------------
__global__ __launch_bounds__(256) void o_del_k(
    const float* __restrict__ y, const float* __restrict__ odw,
    const float* __restrict__ odb, float* __restrict__ out_odel, int HW)
{
    int s = blockIdx.x * 256 + threadIdx.x;
    int n = blockIdx.y;
    if (s >= HW) return;
    const float* yp = y + (size_t)n * 256 * HW + s;
    float acc[12];
#pragma unroll
    for (int a = 0; a < 12; ++a) acc[a] = 0.f;
    for (int c = 0; c < 256; ++c) {
        float v = yp[(size_t)c * HW];
#pragma unroll
        for (int a = 0; a < 12; ++a) acc[a] = fmaf(odw[a * 256 + c], v, acc[a]);
    }
#pragma unroll
    for (int a = 0; a < 12; ++a)
        out_odel[((size_t)n * 12 + a) * HW + s] = acc[a] + odb[a];
}

// ---------------- per-level top-20 (value desc, tie -> lower index) ---------
__global__ __launch_bounds__(256) void topk_level_k(
    const float* __restrict__ scores, float* __restrict__ lv_sc,
    int* __restrict__ lv_ix, int4 hws, int4 soffs)
{
    int l = blockIdx.x, n = blockIdx.y;
    int HW = (l == 0) ? hws.x : (l == 1) ? hws.y : (l == 2) ? hws.z : hws.w;
    int so = (l == 0) ? soffs.x : (l == 1) ? soffs.y : (l == 2) ? soffs.z : soffs.w;
    __shared__ float sc[10240];
    __shared__ float rv[256];
    __shared__ int   ri[256];
    int tid = threadIdx.x;
    for (int i = tid; i < HW; i += 256) sc[i] = scores[so + (size_t)n * HW + i];
    __syncthreads();
    for (int r = 0; r < 20; ++r) {
        float bv = -INFINITY; int bi = 0x7fffffff;
        for (int i = tid; i < HW; i += 256) {
            float v = sc[i];
            if (v > bv || (v == bv && i < bi)) { bv = v; bi = i; }
        }
        rv[tid] = bv; ri[tid] = bi;
        __syncthreads();
        for (int off = 128; off > 0; off >>= 1) {
            if (tid < off) {
                float v2 = rv[tid + off]; int i2 = ri[tid + off];
                if (v2 > rv[tid] || (v2 == rv[tid] && i2 < ri[tid])) {
                    rv[tid] = v2; ri[tid] = i2;
                }
            }
            __syncthreads();
        }
        if (tid == 0) {
            int idx = (n * 4 + l) * 20 + r;
            lv_sc[idx] = rv[0];
            lv_ix[idx] = ri[0];
            sc[ri[0]] = -INFINITY;
        }
        __syncthreads();
    }
}

// ---------------- global top-20 of 80 + gather pf ---------------------------
__global__ __launch_bounds__(256) void select_gather_k(
    const float* __restrict__ lv_sc, const int* __restrict__ lv_ix,
    const float* __restrict__ hid, float* __restrict__ pf,
    int4 hws, int4 hoffs)
{
    int n = blockIdx.x;
    __shared__ float gsc[80];
    __shared__ int   gcell[80];
    __shared__ int   selL[20], selC[20];
    __shared__ float rv[256];
    __shared__ int   ri[256];
    int tid = threadIdx.x;
    if (tid < 80) {
        gsc[tid] = lv_sc[n * 80 + tid];
        gcell[tid] = lv_ix[n * 80 + tid];
    }
    __syncthreads();
    for (int r = 0; r < 20; ++r) {
        float bv = -INFINITY; int bi = 0x7fffffff;
        if (tid < 80) { bv = gsc[tid]; bi = tid; }
        rv[tid] = bv; ri[tid] = bi;
        __syncthreads();
        for (int off = 128; off > 0; off >>= 1) {
            if (tid < off) {
                float v2 = rv[tid + off]; int i2 = ri[tid + off];
                if (v2 > rv[tid] || (v2 == rv[tid] && i2 < ri[tid])) {
                    rv[tid] = v2; ri[tid] = i2;
                }
            }
            __syncthreads();
        }
        if (tid == 0) {
            int j = ri[0];
            selL[r] = j / 20;
            selC[r] = gcell[j];
            gsc[j] = -INFINITY;
        }
        __syncthreads();
    }
    for (int t = tid; t < 20 * 256; t += 256) {
        int k = t >> 8, c = t & 255;
        int l = selL[k], cell = selC[k];
        int HW = (l == 0) ? hws.x : (l == 1) ? hws.y : (l == 2) ? hws.z : hws.w;
        int ho = (l == 0) ? hoffs.x : (l == 1) ? hoffs.y : (l == 2) ? hoffs.z : hoffs.w;
        pf[((size_t)n * 20 + k) * 256 + c] =
            hid[(size_t)ho + ((size_t)n * 256 + c) * HW + cell];
    }
}

// ---------------- p_proj = pf @ Wp^T + rn1_b --------------------------------
__global__ __launch_bounds__(256) void pproj_k(
    const float* __restrict__ pf, const float* __restrict__ WpT,
    const float* __restrict__ rn1b, float* __restrict__ pp)
{
    int nk = blockIdx.x;
    int t = threadIdx.x;
    __shared__ float f[256];
    f[t] = pf[(size_t)nk * 256 + t];
    __syncthreads();
    float acc = rn1b[t];
    for (int c = 0; c < 256; ++c) acc = fmaf(f[c], WpT[c * 256 + t], acc);
    pp[(size_t)nk * 256 + t] = acc;
}

// ---------------- fused o_proj + sum_k relu(o_proj + p_proj) ----------------
__global__ __launch_bounds__(256) void oproj_hsum_k(
    const float* __restrict__ y, const float* __restrict__ WoT,
    const float* __restrict__ pp, float* __restrict__ hsum, int HW)
{
    int n = blockIdx.y;
    int s0 = blockIdx.x * 64;
    int tid = threadIdx.x;
    int dq = tid & 63, sg = tid >> 6;

    __shared__ float ylds[32][64];
    __shared__ float pplds[20 * 256];

    for (int i = tid; i < 20 * 256; i += 256) pplds[i] = pp[(size_t)n * 20 * 256 + i];

    const float* yb = y + (size_t)n * 256 * HW;
    float acc[4][16];
#pragma unroll
    for (int i = 0; i < 4; ++i)
#pragma unroll
        for (int j = 0; j < 16; ++j) acc[i][j] = 0.f;

    for (int cb = 0; cb < 256; cb += 32) {
        __syncthreads();
        for (int idx = tid; idx < 32 * 64; idx += 256) {
            int i = idx >> 6, j = idx & 63;
            int s = s0 + j;
            ylds[i][j] = (s < HW) ? yb[(size_t)(cb + i) * HW + s] : 0.f;
        }
        __syncthreads();
#pragma unroll 4
        for (int i = 0; i < 32; ++i) {
            float4 w4 = *(const float4*)&WoT[(size_t)(cb + i) * 256 + dq * 4];
            const float4* yr4 = (const float4*)&ylds[i][sg * 16];
#pragma unroll
            for (int jj = 0; jj < 4; ++jj) {
                float4 y4 = yr4[jj];
                int j = jj * 4;
                acc[0][j+0] = fmaf(w4.x, y4.x, acc[0][j+0]);
                acc[1][j+0] = fmaf(w4.y, y4.x, acc[1][j+0]);
                acc[2][j+0] = fmaf(w4.z, y4.x, acc[2][j+0]);
                acc[3][j+0] = fmaf(w4.w, y4.x, acc[3][j+0]);
                acc[0][j+1] = fmaf(w4.x, y4.y, acc[0][j+1]);
                acc[1][j+1] = fmaf(w4.y, y4.y, acc[1][j+1]);
                acc[2][j+1] = fmaf(w4.z, y4.y, acc[2][j+1]);
                acc[3][j+1] = fmaf(w4.w, y4.y, acc[3][j+1]);
                acc[0][j+2] = fmaf(w4.x, y4.z, acc[0][j+2]);
                acc[1][j+2] = fmaf(w4.y, y4.z, acc[1][j+2]);
                acc[2][j+2] = fmaf(w4.z, y4.z, acc[2][j+2]);
                acc[3][j+2] = fmaf(w4.w, y4.z, acc[3][j+2]);
                acc[0][j+3] = fmaf(w4.x, y4.w, acc[0][j+3]);
                acc[1][j+3] = fmaf(w4.y, y4.w, acc[1][j+3]);
                acc[2][j+3] = fmaf(w4.z, y4.w, acc[2][j+3]);
                acc[3][j+3] = fmaf(w4.w, y4.w, acc[3][j+3]);
            }
        }
    }
#pragma unroll
    for (int i = 0; i < 4; ++i) {
        int d = dq * 4 + i;
        float pk[20];
#pragma unroll
        for (int k = 0; k < 20; ++k) pk[k] = pplds[k * 256 + d];
#pragma unroll
        for (int j = 0; j < 16; ++j) {
            float v = acc[i][j];
            float h = 0.f;
#pragma unroll
            for (int k = 0; k < 20; ++k) h += fmaxf(v + pk[k], 0.f);
            acc[i][j] = h;
        }
    }
#pragma unroll
    for (int j = 0; j < 16; ++j) {
        int s = s0 + sg * 16 + j;
        if (s < HW) {
            float4 o = make_float4(acc[0][j], acc[1][j], acc[2][j], acc[3][j]);
            *(float4*)&hsum[((size_t)n * HW + s) * 256 + dq * 4] = o;
        }
    }
}

// ---------------- rn2 GEMM + relu + ol head, per 16-s tile ------------------
__global__ __launch_bounds__(256) void rn2_ol_k(
    const float* __restrict__ hsum, const float* __restrict__ rn2T,
    const float* __restrict__ rn2b, const float* __restrict__ olw,
    const float* __restrict__ olb, float* __restrict__ out_olog, int HW)
{
    int n = blockIdx.y;
    int s0 = blockIdx.x * 16;
    int tid = threadIdx.x;
    int dq = tid & 63, sg = tid >> 6;

    __shared__ float hsT[256 * 16];
    __shared__ float h2L[16][257];

    const float* hb = hsum + ((size_t)n * HW + s0) * 256;
#pragma unroll
    for (int i = 0; i < 16; ++i) hsT[tid * 16 + i] = hb[(size_t)i * 256 + tid];
    __syncthreads();

    float acc[4][4];
#pragma unroll
    for (int i = 0; i < 4; ++i)
#pragma unroll
        for (int j = 0; j < 4; ++j) acc[i][j] = 0.f;

    for (int kk = 0; kk < 256; ++kk) {
        float4 w4 = *(const float4*)&rn2T[(size_t)kk * 256 + dq * 4];
        float4 h4 = *(const float4*)&hsT[kk * 16 + sg * 4];
        acc[0][0] = fmaf(w4.x, h4.x, acc[0][0]); acc[0][1] = fmaf(w4.x, h4.y, acc[0][1]);
        acc[0][2] = fmaf(w4.x, h4.z, acc[0][2]); acc[0][3] = fmaf(w4.x, h4.w, acc[0][3]);
        acc[1][0] = fmaf(w4.y, h4.x, acc[1][0]); acc[1][1] = fmaf(w4.y, h4.y, acc[1][1]);
        acc[1][2] = fmaf(w4.y, h4.z, acc[1][2]); acc[1][3] = fmaf(w4.y, h4.w, acc[1][3]);
        acc[2][0] = fmaf(w4.z, h4.x, acc[2][0]); acc[2][1] = fmaf(w4.z, h4.y, acc[2][1]);
        acc[2][2] = fmaf(w4.z, h4.z, acc[2][2]); acc[2][3] = fmaf(w4.z, h4.w, acc[2][3]);
        acc[3][0] = fmaf(w4.w, h4.x, acc[3][0]); acc[3][1] = fmaf(w4.w, h4.y, acc[3][1]);
        acc[3][2] = fmaf(w4.w, h4.z, acc[3][2]); acc[3][3] = fmaf(w4.w, h4.w, acc[3][3]);
    }
#pragma unroll
    for (int i = 0; i < 4; ++i) {
        float bb = rn2b[dq * 4 + i];
#pragma unroll
        for (int j = 0; j < 4; ++j)
            h2L[sg * 4 + j][dq * 4 + i] = fmaxf(acc[i][j] + bb, 0.f);
    }
    __syncthreads();
    if (tid < 48) {
        int s = tid / 3, a = tid - (tid / 3) * 3;
        float acc2 = olb[a];
        for (int d = 0; d < 256; ++d) acc2 = fmaf(olw[a * 256 + d], h2L[s][d], acc2);
        out_olog[((size_t)n * 3 + a) * HW + s0 + s] = acc2;
    }
}

// ---------------- weight transposes ----------------------------------------
__global__ __launch_bounds__(256) void prep_w_k(
    const float* __restrict__ rn1w, const float* __restrict__ rn2w,
    float* __restrict__ WoT, float* __restrict__ WpT, float* __restrict__ rn2T)
{
    int d = blockIdx.x;
    int c = threadIdx.x;
    WoT[c * 256 + d] = rn1w[(size_t)d * 512 + c];
    WpT[c * 256 + d] = rn1w[(size_t)d * 512 + 256 + c];
    rn2T[c * 256 + d] = rn2w[(size_t)d * 256 + c];
}

extern "C" void kernel_launch(void* const* d_in, const int* in_sizes, int n_in,
                              void* d_out, int out_size, void* d_ws, size_t ws_size,
                              hipStream_t stream)
{
    const float* feat[4] = {(const float*)d_in[0], (const float*)d_in[1],
                            (const float*)d_in[2], (const float*)d_in[3]};
    const float* pc1w = (const float*)d_in[4];  const float* pc1b = (const float*)d_in[5];
    const float* pc2w = (const float*)d_in[6];  const float* pc2b = (const float*)d_in[7];
    const float* oc1w = (const float*)d_in[8];  const float* oc1b = (const float*)d_in[9];
    const float* oc2w = (const float*)d_in[10]; const float* oc2b = (const float*)d_in[11];
    const float* rn1w = (const float*)d_in[12]; const float* rn1b = (const float*)d_in[13];
    const float* rn2w = (const float*)d_in[14]; const float* rn2b = (const float*)d_in[15];
    const float* plw  = (const float*)d_in[16]; const float* plb  = (const float*)d_in[17];
    const float* pdw  = (const float*)d_in[18]; const float* pdb  = (const float*)d_in[19];
    const float* olw  = (const float*)d_in[20]; const float* olb  = (const float*)d_in[21];
    const float* odw  = (const float*)d_in[22]; const float* odb  = (const float*)d_in[23];

    float* ws = (float*)d_ws;
    float* big0   = ws;                    // p_hid all levels / o-branch y
    float* big1   = ws + 6963200;          // conv tmp / hsum
    float* scores = ws + 12206080;
    float* lv_sc  = ws + 12233280;
    int*   lv_ix  = (int*)(ws + 12233440);
    float* pf     = ws + 12233600;
    float* pp     = ws + 12243840;
    float* WoT    = ws + 12254080;
    float* WpT    = ws + 12319616;
    float* rn2T   = ws + 12385152;
    __bf16* wtap  = (__bf16*)(ws + 12450688);   // 4 x 589824 bf16
    __bf16* wt_pc1 = wtap;
    __bf16* wt_pc2 = wtap + 589824;
    __bf16* wt_oc1 = wtap + 2 * 589824;
    __bf16* wt_oc2 = wtap + 3 * 589824;

    const int Hs[4] = {80, 40, 20, 10}, Wsz[4] = {128, 64, 32, 16};
    const int lg2W[4] = {7, 6, 5, 4};
    const int HWs[4] = {10240, 2560, 640, 160};
    const size_t hoff[4] = {0, 5242880, 6553600, 6881280};
    const int soff[4] = {0, 20480, 25600, 26880};
    float* out = (float*)d_out;
    const size_t plog_off[4] = {0, 61440, 76800, 80640};
    const size_t pdel_off[4] = {81600, 327360, 388800, 404160};
    const size_t olog_off[4] = {408000, 469440, 484800, 488640};
    const size_t odel_off[4] = {489600, 735360, 796800, 812160};

    hipLaunchKernelGGL(prep_w_k, dim3(256), dim3(256), 0, stream,
                       rn1w, rn2w, WoT, WpT, rn2T);
    hipLaunchKernelGGL(prep_wtap_k, dim3(9, 256), dim3(256), 0, stream, pc1w, wt_pc1);
    hipLaunchKernelGGL(prep_wtap_k, dim3(9, 256), dim3(256), 0, stream, pc2w, wt_pc2);
    hipLaunchKernelGGL(prep_wtap_k, dim3(9, 256), dim3(256), 0, stream, oc1w, wt_oc1);
    hipLaunchKernelGGL(prep_wtap_k, dim3(9, 256), dim3(256), 0, stream, oc2w, wt_oc2);

    // ---------------- p-branch ----------------
    for (int l = 0; l < 4; ++l) {
        int H = Hs[l], W = Wsz[l], HW = HWs[l];
        dim3 gconv((unsigned)((HW + 255) >> 8), 4, 2);
        hipLaunchKernelGGL(conv3x3_mfma_k, gconv, dim3(256), 0, stream,
                           feat[l], wt_pc1, pc1b, big1, H, W, lg2W[l], HW, 1);
        hipLaunchKernelGGL(conv3x3_mfma_k, gconv, dim3(256), 0, stream,
                           big1, wt_pc2, pc2b, big0 + hoff[l], H, W, lg2W[l], HW, 1);
        dim3 gh((unsigned)((HW + 255) / 256), 2);
        hipLaunchKernelGGL(p_heads_k, gh, dim3(256), 0, stream,
                           big0 + hoff[l], plw, plb, pdw, pdb,
                           out + plog_off[l], out + pdel_off[l], scores + soff[l], HW);
    }

    hipLaunchKernelGGL(topk_level_k, dim3(4, 2), dim3(256), 0, stream,
                       scores, lv_sc, lv_ix,
                       make_int4(10240, 2560, 640, 160),
                       make_int4(0, 20480, 25600, 26880));
    hipLaunchKernelGGL(select_gather_k, dim3(2), dim3(256), 0, stream,
                       lv_sc, lv_ix, big0, pf,
                       make_int4(10240, 2560, 640, 160),
                       make_int4(0, 5242880, 6553600, 6881280));
    hipLaunchKernelGGL(pproj_k, dim3(40), dim3(256), 0, stream, pf, WpT, rn1b, pp);

    // ---------------- o-branch ----------------
    for (int l = 0; l < 4; ++l) {
        int H = Hs[l], W = Wsz[l], HW = HWs[l];
        dim3 gconv((unsigned)((HW + 255) >> 8), 4, 2);
        hipLaunchKernelGGL(conv3x3_mfma_k, gconv, dim3(256), 0, stream,
                           feat[l], wt_oc1, oc1b, big1, H, W, lg2W[l], HW, 1);
        hipLaunchKernelGGL(conv3x3_mfma_k, gconv, dim3(256), 0, stream,
                           big1, wt_oc2, oc2b, big0 + hoff[l], H, W, lg2W[l], HW, 1);
        dim3 gh((unsigned)((HW + 255) / 256), 2);
        hipLaunchKernelGGL(o_del_k, gh, dim3(256), 0, stream,
                           big0 + hoff[l], odw, odb, out + odel_off[l], HW);
        hipLaunchKernelGGL(oproj_hsum_k, dim3((unsigned)((HW + 63) / 64), 2), dim3(256), 0, stream,
                           big0 + hoff[l], WoT, pp, big1, HW);
        hipLaunchKernelGGL(rn2_ol_k, dim3((unsigned)(HW / 16), 2), dim3(256), 0, stream,
                           big1, rn2T, rn2b, olw, olb, out + olog_off[l], HW);
    }
}

// Round 3
// 669.757 us; speedup vs baseline: 13.5495x; 4.5027x over previous
//
#include <hip/hip_runtime.h>
#include <cstdint>
#include <cstddef>

typedef __bf16 bf16x8 __attribute__((ext_vector_type(8)));
typedef float  f32x16 __attribute__((ext_vector_type(16)));

union U16 { bf16x8 v; uint4 q; };
union U8  { __bf16 h[4]; unsigned long long u; };

// level helpers (256-pixel tiles): tile counts 40,10,3,1 -> bounds 40,50,53,54
__device__ __forceinline__ int lvl256(int bx) {
    return (bx < 40) ? 0 : (bx < 50) ? 1 : (bx < 53) ? 2 : 3;
}
__device__ __forceinline__ int tbase256(int lv) {
    return (lv == 0) ? 0 : (lv == 1) ? 40 : (lv == 2) ? 50 : 53;
}
__device__ __forceinline__ size_t loffE(int lv) {   // bf16-element offset of level block
    return (lv == 0) ? 0 : (lv == 1) ? 5242880 : (lv == 2) ? 6553600 : 6881280;
}
__device__ __forceinline__ size_t plog_off(int lv) {
    return (lv == 0) ? 0 : (lv == 1) ? 61440 : (lv == 2) ? 76800 : 80640;
}
__device__ __forceinline__ size_t pdel_off(int lv) {
    return (lv == 0) ? 81600 : (lv == 1) ? 327360 : (lv == 2) ? 388800 : 404160;
}
__device__ __forceinline__ size_t olog_off(int lv) {
    return (lv == 0) ? 408000 : (lv == 1) ? 469440 : (lv == 2) ? 484800 : 488640;
}
__device__ __forceinline__ size_t odel_off(int lv) {
    return (lv == 0) ? 489600 : (lv == 1) ? 735360 : (lv == 2) ? 796800 : 812160;
}
__device__ __forceinline__ int soff_l(int lv) {
    return (lv == 0) ? 0 : (lv == 1) ? 20480 : (lv == 2) ? 25600 : 26880;
}

// ---------------- weight prep: conv taps fp32 [co][ci][3][3] -> bf16 [t][co][ci]
__global__ __launch_bounds__(256) void prep_wtap_k(
    const float* w0, const float* w1, const float* w2, const float* w3,
    __bf16* d0, __bf16* d1, __bf16* d2, __bf16* d3)
{
    int t = blockIdx.x % 9, which = blockIdx.x / 9;
    int co = blockIdx.y, ci = threadIdx.x;
    const float* src = (which == 0) ? w0 : (which == 1) ? w1 : (which == 2) ? w2 : w3;
    __bf16* dst = (which == 0) ? d0 : (which == 1) ? d1 : (which == 2) ? d2 : d3;
    dst[(size_t)(t * 256 + co) * 256 + ci] = (__bf16)src[(size_t)(co * 256 + ci) * 9 + t];
}

// ---------------- relnet weight prep: WpT fp32, Wo16/rn216 bf16 interleaved ---
__global__ __launch_bounds__(256) void prep_rel_k(
    const float* __restrict__ rn1w, const float* __restrict__ rn2w,
    float* __restrict__ WpT, __bf16* __restrict__ Wo16, __bf16* __restrict__ rn216)
{
    int d = blockIdx.x, c = threadIdx.x;
    WpT[c * 256 + d] = rn1w[(size_t)d * 512 + 256 + c];
    Wo16[((c >> 4) * 256 + d) * 16 + (c & 15)] = (__bf16)rn1w[(size_t)d * 512 + c];
    rn216[((c >> 4) * 256 + d) * 16 + (c & 15)] = (__bf16)rn2w[(size_t)d * 256 + c];
}

// ---------------- feats fp32 planar -> bf16 interleaved [ch16][pixel][16] ----
__global__ __launch_bounds__(256) void feat2x16_k(
    const float* f0, const float* f1, const float* f2, const float* f3,
    __bf16* __restrict__ x16)
{
    int bx = blockIdx.x, n = blockIdx.y, z = blockIdx.z;
    int lv = lvl256(bx);
    int HW = 10240 >> (2 * lv);
    int p = (bx - tbase256(lv)) * 256 + threadIdx.x;
    if (p >= HW) return;
    const float* f = (lv == 0) ? f0 : (lv == 1) ? f1 : (lv == 2) ? f2 : f3;
    int ch = z >> 1, u = z & 1;
    const float* src = f + (size_t)n * 256 * HW + (size_t)(ch * 16 + u * 8) * HW + p;
    U16 v;
#pragma unroll
    for (int j = 0; j < 8; ++j) v.v[j] = (__bf16)src[(size_t)j * HW];
    *(uint4*)&x16[loffE(lv) + (size_t)n * HW * 256 + (((size_t)ch * HW + p) << 4) + (u << 3)] = v.q;
}

// ---------------- conv 3x3 SAME, bf16-interleaved in/out, MFMA ---------------
// grid: (54 tiles all levels, 4 co-groups, 2 or 4 [n x branch])
__global__ __launch_bounds__(256) void conv3x3_v2(
    const __bf16* __restrict__ in16,
    const __bf16* __restrict__ wt0, const __bf16* __restrict__ wt1,
    const float* __restrict__ b0p, const float* __restrict__ b1p,
    __bf16* __restrict__ out0, __bf16* __restrict__ out1)
{
    __shared__ __bf16 Asm[9 * 64 * 24];   // [t][co][ci16] pitch 24 (48B rows)
    __shared__ __bf16 Bsm[12480];         // [halo-pixel][ci16] pitch 24

    const int tid = threadIdx.x;
    const int zz = blockIdx.z;
    const int n = zz & 1, br = zz >> 1;
    const __bf16* wt = br ? wt1 : wt0;
    const float* bias = br ? b1p : b0p;
    __bf16* outp = br ? out1 : out0;

    const int bx = blockIdx.x;
    const int lv = lvl256(bx);
    const int lg2W = 7 - lv;
    const int W = 1 << lg2W, H = 80 >> lv;
    const int HW = 10240 >> (2 * lv);
    const size_t ioff = loffE(lv) + (size_t)n * HW * 256;

    const int tile = bx - tbase256(lv);
    const int sp0 = tile << 8;
    const int npix = min(256, HW - sp0);
    const int R = npix >> lg2W;
    const int Hrows = R + 2, HC = W + 2;
    const int y0 = sp0 >> lg2W;

    const int cobase = blockIdx.y << 6;
    const int w = tid >> 6, l64 = tid & 63;
    const int lane = l64 & 31, half = l64 >> 5;
    const int pix0 = (w << 6) + lane, pix1 = pix0 + 32;
    const int py0 = pix0 >> lg2W, px0 = pix0 & (W - 1);
    const int py1 = pix1 >> lg2W, px1 = pix1 & (W - 1);
    const int hp0 = py0 * HC + px0;
    const int hp1 = py1 * HC + px1;

    f32x16 acc00 = {}, acc01 = {}, acc10 = {}, acc11 = {};
    const int unitsB = Hrows * HC * 2;

    for (int cb = 0; cb < 256; cb += 16) {
        const int cb16 = cb >> 4;
        __syncthreads();
        // stage A: 9 x 64co x 16ci in 16B units
        for (int i = tid; i < 1152; i += 256) {
            int t = i >> 7, r = i & 127, co = r >> 1, hf = r & 1;
            *(uint4*)&Asm[(t * 64 + co) * 24 + (hf << 3)] =
                *(const uint4*)&wt[(((size_t)(t * 256 + cobase + co)) << 8) + cb + (hf << 3)];
        }
        // stage B: halo pixels, 2 x 16B units each
        for (int i = tid; i < unitsB; i += 256) {
            int u = i & 1, hp = i >> 1;
            int hy = hp / HC, hx = hp - hy * HC;
            int gy = y0 + hy - 1, gx = hx - 1;
            U16 v; v.q = make_uint4(0, 0, 0, 0);
            if ((unsigned)gy < (unsigned)H && (unsigned)gx < (unsigned)W) {
                int p = (gy << lg2W) + gx;
                v.q = *(const uint4*)&in16[ioff + (((size_t)cb16 * HW + p) << 4) + (u << 3)];
            }
            *(uint4*)&Bsm[hp * 24 + (u << 3)] = v.q;
        }
        __syncthreads();
#pragma unroll
        for (int dy = 0; dy < 3; ++dy) {
#pragma unroll
            for (int dx = 0; dx < 3; ++dx) {
                const int t = dy * 3 + dx;
                bf16x8 a0 = *(const bf16x8*)&Asm[(t * 64 + lane) * 24 + (half << 3)];
                bf16x8 a1 = *(const bf16x8*)&Asm[(t * 64 + 32 + lane) * 24 + (half << 3)];
                bf16x8 b0 = *(const bf16x8*)&Bsm[(hp0 + dy * HC + dx) * 24 + (half << 3)];
                bf16x8 b1 = *(const bf16x8*)&Bsm[(hp1 + dy * HC + dx) * 24 + (half << 3)];
                acc00 = __builtin_amdgcn_mfma_f32_32x32x16_bf16(a0, b0, acc00, 0, 0, 0);
                acc01 = __builtin_amdgcn_mfma_f32_32x32x16_bf16(a0, b1, acc01, 0, 0, 0);
                acc10 = __builtin_amdgcn_mfma_f32_32x32x16_bf16(a1, b0, acc10, 0, 0, 0);
                acc11 = __builtin_amdgcn_mfma_f32_32x32x16_bf16(a1, b1, acc11, 0, 0, 0);
            }
        }
    }
    // epilogue: C/D col=lane (pixel), row=(reg&3)+8*(reg>>2)+4*half (co); bf16 pack
    const int pixg0 = sp0 + pix0, pixg1 = sp0 + pix1;
    const bool ok0 = (pix0 < npix), ok1 = (pix1 < npix);
#pragma unroll
    for (int b = 0; b < 2; ++b) {
        const f32x16& A0 = b ? acc10 : acc00;
        const f32x16& A1 = b ? acc11 : acc01;
#pragma unroll
        for (int q = 0; q < 4; ++q) {
            int co0 = cobase + b * 32 + q * 8 + half * 4;
            float4 bq = *(const float4*)&bias[co0];
            U8 v0, v1;
            v0.h[0] = (__bf16)fmaxf(A0[q * 4 + 0] + bq.x, 0.f);
            v0.h[1] = (__bf16)fmaxf(A0[q * 4 + 1] + bq.y, 0.f);
            v0.h[2] = (__bf16)fmaxf(A0[q * 4 + 2] + bq.z, 0.f);
            v0.h[3] = (__bf16)fmaxf(A0[q * 4 + 3] + bq.w, 0.f);
            v1.h[0] = (__bf16)fmaxf(A1[q * 4 + 0] + bq.x, 0.f);
            v1.h[1] = (__bf16)fmaxf(A1[q * 4 + 1] + bq.y, 0.f);
            v1.h[2] = (__bf16)fmaxf(A1[q * 4 + 2] + bq.z, 0.f);
            v1.h[3] = (__bf16)fmaxf(A1[q * 4 + 3] + bq.w, 0.f);
            size_t base = ioff + (((size_t)(co0 >> 4) * HW) << 4) + (co0 & 15);
            if (ok0) *(unsigned long long*)&outp[base + ((size_t)pixg0 << 4)] = v0.u;
            if (ok1) *(unsigned long long*)&outp[base + ((size_t)pixg1 << 4)] = v1.u;
        }
    }
}

// ---------------- p-branch 1x1 heads (batched levels) -----------------------
__global__ __launch_bounds__(256) void p_heads_v2(
    const __bf16* __restrict__ h16, const float* __restrict__ plw,
    const float* __restrict__ plb, const float* __restrict__ pdw,
    const float* __restrict__ pdb, float* __restrict__ out,
    float* __restrict__ scores)
{
    int bx = blockIdx.x, n = blockIdx.y;
    int lv = lvl256(bx);
    int HW = 10240 >> (2 * lv);
    int p = (bx - tbase256(lv)) * 256 + threadIdx.x;
    if (p >= HW) return;
    size_t ioff = loffE(lv) + (size_t)n * HW * 256;
    float acc[15];
#pragma unroll
    for (int a = 0; a < 15; ++a) acc[a] = 0.f;
    for (int ch = 0; ch < 16; ++ch) {
        size_t base = ioff + (((size_t)ch * HW + p) << 4);
        bf16x8 v0 = *(const bf16x8*)&h16[base];
        bf16x8 v1 = *(const bf16x8*)&h16[base + 8];
#pragma unroll
        for (int j = 0; j < 16; ++j) {
            float vv = (j < 8) ? (float)v0[j] : (float)v1[j - 8];
            int c = ch * 16 + j;
#pragma unroll
            for (int a = 0; a < 3; ++a)  acc[a]     = fmaf(plw[a * 256 + c], vv, acc[a]);
#pragma unroll
            for (int a = 0; a < 12; ++a) acc[3 + a] = fmaf(pdw[a * 256 + c], vv, acc[3 + a]);
        }
    }
    float sc = -INFINITY;
#pragma unroll
    for (int a = 0; a < 3; ++a) {
        float lg = acc[a] + plb[a];
        out[plog_off(lv) + ((size_t)n * 3 + a) * HW + p] = lg;
        sc = fmaxf(sc, lg);
    }
    scores[soff_l(lv) + (size_t)n * HW + p] = sc;
#pragma unroll
    for (int a = 0; a < 12; ++a)
        out[pdel_off(lv) + ((size_t)n * 12 + a) * HW + p] = acc[3 + a] + pdb[a];
}

// ---------------- o-branch 1x1 head o_del (batched levels) ------------------
__global__ __launch_bounds__(256) void o_del_v2(
    const __bf16* __restrict__ h16, const float* __restrict__ odw,
    const float* __restrict__ odb, float* __restrict__ out)
{
    int bx = blockIdx.x, n = blockIdx.y;
    int lv = lvl256(bx);
    int HW = 10240 >> (2 * lv);
    int p = (bx - tbase256(lv)) * 256 + threadIdx.x;
    if (p >= HW) return;
    size_t ioff = loffE(lv) + (size_t)n * HW * 256;
    float acc[12];
#pragma unroll
    for (int a = 0; a < 12; ++a) acc[a] = 0.f;
    for (int ch = 0; ch < 16; ++ch) {
        size_t base = ioff + (((size_t)ch * HW + p) << 4);
        bf16x8 v0 = *(const bf16x8*)&h16[base];
        bf16x8 v1 = *(const bf16x8*)&h16[base + 8];
#pragma unroll
        for (int j = 0; j < 16; ++j) {
            float vv = (j < 8) ? (float)v0[j] : (float)v1[j - 8];
            int c = ch * 16 + j;
#pragma unroll
            for (int a = 0; a < 12; ++a) acc[a] = fmaf(odw[a * 256 + c], vv, acc[a]);
        }
    }
#pragma unroll
    for (int a = 0; a < 12; ++a)
        out[odel_off(lv) + ((size_t)n * 12 + a) * HW + p] = acc[a] + odb[a];
}

// ---------------- per-level top-20 ------------------------------------------
__global__ __launch_bounds__(256) void topk_level_k(
    const float* __restrict__ scores, float* __restrict__ lv_sc,
    int* __restrict__ lv_ix)
{
    int l = blockIdx.x, n = blockIdx.y;
    int HW = 10240 >> (2 * l);
    int so = soff_l(l);
    __shared__ float sc[10240];
    __shared__ float rv[256];
    __shared__ int   ri[256];
    int tid = threadIdx.x;
    for (int i = tid; i < HW; i += 256) sc[i] = scores[so + (size_t)n * HW + i];
    __syncthreads();
    for (int r = 0; r < 20; ++r) {
        float bv = -INFINITY; int bi = 0x7fffffff;
        for (int i = tid; i < HW; i += 256) {
            float v = sc[i];
            if (v > bv || (v == bv && i < bi)) { bv = v; bi = i; }
        }
        rv[tid] = bv; ri[tid] = bi;
        __syncthreads();
        for (int off = 128; off > 0; off >>= 1) {
            if (tid < off) {
                float v2 = rv[tid + off]; int i2 = ri[tid + off];
                if (v2 > rv[tid] || (v2 == rv[tid] && i2 < ri[tid])) {
                    rv[tid] = v2; ri[tid] = i2;
                }
            }
            __syncthreads();
        }
        if (tid == 0) {
            int idx = (n * 4 + l) * 20 + r;
            lv_sc[idx] = rv[0];
            lv_ix[idx] = ri[0];
            sc[ri[0]] = -INFINITY;
        }
        __syncthreads();
    }
}

// ---------------- global top-20 of 80 + gather pf (bf16 hidden) -------------
__global__ __launch_bounds__(256) void select_gather_v2(
    const float* __restrict__ lv_sc, const int* __restrict__ lv_ix,
    const __bf16* __restrict__ h16, float* __restrict__ pf)
{
    int n = blockIdx.x;
    __shared__ float gsc[80];
    __shared__ int   gcell[80];
    __shared__ int   selL[20], selC[20];
    __shared__ float rv[256];
    __shared__ int   ri[256];
    int tid = threadIdx.x;
    if (tid < 80) {
        gsc[tid] = lv_sc[n * 80 + tid];
        gcell[tid] = lv_ix[n * 80 + tid];
    }
    __syncthreads();
    for (int r = 0; r < 20; ++r) {
        float bv = -INFINITY; int bi = 0x7fffffff;
        if (tid < 80) { bv = gsc[tid]; bi = tid; }
        rv[tid] = bv; ri[tid] = bi;
        __syncthreads();
        for (int off = 128; off > 0; off >>= 1) {
            if (tid < off) {
                float v2 = rv[tid + off]; int i2 = ri[tid + off];
                if (v2 > rv[tid] || (v2 == rv[tid] && i2 < ri[tid])) {
                    rv[tid] = v2; ri[tid] = i2;
                }
            }
            __syncthreads();
        }
        if (tid == 0) {
            int j = ri[0];
            selL[r] = j / 20;
            selC[r] = gcell[j];
            gsc[j] = -INFINITY;
        }
        __syncthreads();
    }
    for (int t = tid; t < 20 * 256; t += 256) {
        int k = t >> 8, c = t & 255;
        int l = selL[k], cell = selC[k];
        int HW = 10240 >> (2 * l);
        pf[((size_t)n * 20 + k) * 256 + c] =
            (float)h16[loffE(l) + (size_t)n * HW * 256 +
                       (((size_t)(c >> 4) * HW + cell) << 4) + (c & 15)];
    }
}

// ---------------- p_proj = pf @ Wp^T + rn1_b (fp32) -------------------------
__global__ __launch_bounds__(256) void pproj_k(
    const float* __restrict__ pf, const float* __restrict__ WpT,
    const float* __restrict__ rn1b, float* __restrict__ pp)
{
    int nk = blockIdx.x;
    int t = threadIdx.x;
    __shared__ float f[256];
    f[t] = pf[(size_t)nk * 256 + t];
    __syncthreads();
    float acc = rn1b[t];
    for (int c = 0; c < 256; ++c) acc = fmaf(f[c], WpT[c * 256 + t], acc);
    pp[(size_t)nk * 256 + t] = acc;
}

// ---------------- fused o_proj + hsum + rn2 + ol (MFMA) ---------------------
// block: 64 pixels, full d=256 / e=256. 64-tile bounds: 160,200,210,213.
__global__ __launch_bounds__(256) void orel_k(
    const __bf16* __restrict__ H16o, const __bf16* __restrict__ Wo16,
    const __bf16* __restrict__ rn216, const float* __restrict__ pp,
    const float* __restrict__ rn2b, const float* __restrict__ olw,
    const float* __restrict__ olb, float* __restrict__ out)
{
    __shared__ __bf16 hb[16 * 64 * 24];   // [dch][px][16 + pad8] pitch 24
    __shared__ __bf16 pp16[5120];
    const int tid = threadIdx.x;
    const int n = blockIdx.y;
    int bx = blockIdx.x;
    int lv = (bx < 160) ? 0 : (bx < 200) ? 1 : (bx < 210) ? 2 : 3;
    int tb = (lv == 0) ? 0 : (lv == 1) ? 160 : (lv == 2) ? 200 : 210;
    int HW = 10240 >> (2 * lv);
    size_t yoff = loffE(lv) + (size_t)n * HW * 256;
    int p0 = (bx - tb) << 6;
    int npix = min(64, HW - p0);

    {
        const float* ps = pp + (size_t)n * 5120;
        for (int i = tid; i < 1280; i += 256) {
            float4 f = *(const float4*)&ps[i * 4];
            U8 v;
            v.h[0] = (__bf16)f.x; v.h[1] = (__bf16)f.y;
            v.h[2] = (__bf16)f.z; v.h[3] = (__bf16)f.w;
            *(unsigned long long*)&pp16[i * 4] = v.u;
        }
    }
    __syncthreads();

    const int w = tid >> 6, l64 = tid & 63;
    const int lane = l64 & 31, half = l64 >> 5;
    const int dbase = w << 6;

    // ---- o_proj: D[d][px] = sum_c Wo[d][c] * y[c][px]
    f32x16 acc00 = {}, acc01 = {}, acc10 = {}, acc11 = {};
    for (int c16 = 0; c16 < 16; ++c16) {
        bf16x8 a0 = *(const bf16x8*)&Wo16[(((c16 << 8) + dbase + lane) << 4) + (half << 3)];
        bf16x8 a1 = *(const bf16x8*)&Wo16[(((c16 << 8) + dbase + 32 + lane) << 4) + (half << 3)];
        bf16x8 b0 = *(const bf16x8*)&H16o[yoff + (((size_t)c16 * HW + p0 + lane) << 4) + (half << 3)];
        bf16x8 b1 = *(const bf16x8*)&H16o[yoff + (((size_t)c16 * HW + p0 + 32 + lane) << 4) + (half << 3)];
        acc00 = __builtin_amdgcn_mfma_f32_32x32x16_bf16(a0, b0, acc00, 0, 0, 0);
        acc01 = __builtin_amdgcn_mfma_f32_32x32x16_bf16(a0, b1, acc01, 0, 0, 0);
        acc10 = __builtin_amdgcn_mfma_f32_32x32x16_bf16(a1, b0, acc10, 0, 0, 0);
        acc11 = __builtin_amdgcn_mfma_f32_32x32x16_bf16(a1, b1, acc11, 0, 0, 0);
    }
    // ---- hsum: h[px][d] = sum_k relu(o + pp[k][d]) -> hb (bf16)
#pragma unroll
    for (int b = 0; b < 2; ++b) {
        const f32x16& A0 = b ? acc10 : acc00;
        const f32x16& A1 = b ? acc11 : acc01;
#pragma unroll
        for (int q = 0; q < 4; ++q) {
            int d0 = dbase + b * 32 + q * 8 + half * 4;
            float h0[4] = {0.f, 0.f, 0.f, 0.f}, h1[4] = {0.f, 0.f, 0.f, 0.f};
            for (int k = 0; k < 20; ++k) {
                U8 pk;
                pk.u = *(const unsigned long long*)&pp16[k * 256 + d0];
#pragma unroll
                for (int j = 0; j < 4; ++j) {
                    float pkv = (float)pk.h[j];
                    h0[j] += fmaxf(A0[q * 4 + j] + pkv, 0.f);
                    h1[j] += fmaxf(A1[q * 4 + j] + pkv, 0.f);
                }
            }
            U8 v0, v1;
#pragma unroll
            for (int j = 0; j < 4; ++j) { v0.h[j] = (__bf16)h0[j]; v1.h[j] = (__bf16)h1[j]; }
            *(unsigned long long*)&hb[((d0 >> 4) * 64 + lane) * 24 + (d0 & 15)] = v0.u;
            *(unsigned long long*)&hb[((d0 >> 4) * 64 + 32 + lane) * 24 + (d0 & 15)] = v1.u;
        }
    }
    __syncthreads();
    // ---- rn2: D[e][px] = sum_d rn2w[e][d] * h[px][d]
    f32x16 e00 = {}, e01 = {}, e10 = {}, e11 = {};
    for (int d16 = 0; d16 < 16; ++d16) {
        bf16x8 a0 = *(const bf16x8*)&rn216[(((d16 << 8) + dbase + lane) << 4) + (half << 3)];
        bf16x8 a1 = *(const bf16x8*)&rn216[(((d16 << 8) + dbase + 32 + lane) << 4) + (half << 3)];
        bf16x8 b0 = *(const bf16x8*)&hb[(d16 * 64 + lane) * 24 + (half << 3)];
        bf16x8 b1 = *(const bf16x8*)&hb[(d16 * 64 + 32 + lane) * 24 + (half << 3)];
        e00 = __builtin_amdgcn_mfma_f32_32x32x16_bf16(a0, b0, e00, 0, 0, 0);
        e01 = __builtin_amdgcn_mfma_f32_32x32x16_bf16(a0, b1, e01, 0, 0, 0);
        e10 = __builtin_amdgcn_mfma_f32_32x32x16_bf16(a1, b0, e10, 0, 0, 0);
        e11 = __builtin_amdgcn_mfma_f32_32x32x16_bf16(a1, b1, e11, 0, 0, 0);
    }
    __syncthreads();   // hb reads done before overwrite
    // ---- h2 = relu(rn2out + rn2b) -> hb
#pragma unroll
    for (int b = 0; b < 2; ++b) {
        const f32x16& A0 = b ? e10 : e00;
        const f32x16& A1 = b ? e11 : e01;
#pragma unroll
        for (int q = 0; q < 4; ++q) {
            int e0 = dbase + b * 32 + q * 8 + half * 4;
            float4 bb = *(const float4*)&rn2b[e0];
            U8 v0, v1;
            v0.h[0] = (__bf16)fmaxf(A0[q * 4 + 0] + bb.x, 0.f);
            v0.h[1] = (__bf16)fmaxf(A0[q * 4 + 1] + bb.y, 0.f);
            v0.h[2] = (__bf16)fmaxf(A0[q * 4 + 2] + bb.z, 0.f);
            v0.h[3] = (__bf16)fmaxf(A0[q * 4 + 3] + bb.w, 0.f);
            v1.h[0] = (__bf16)fmaxf(A1[q * 4 + 0] + bb.x, 0.f);
            v1.h[1] = (__bf16)fmaxf(A1[q * 4 + 1] + bb.y, 0.f);
            v1.h[2] = (__bf16)fmaxf(A1[q * 4 + 2] + bb.z, 0.f);
            v1.h[3] = (__bf16)fmaxf(A1[q * 4 + 3] + bb.w, 0.f);
            *(unsigned long long*)&hb[((e0 >> 4) * 64 + lane) * 24 + (e0 & 15)] = v0.u;
            *(unsigned long long*)&hb[((e0 >> 4) * 64 + 32 + lane) * 24 + (e0 & 15)] = v1.u;
        }
    }
    __syncthreads();
    // ---- ol head: o_log[a][px] = sum_e olw[a][e] * h2[e][px] + olb[a]
    if (tid < 192) {
        int px = tid / 3, a = tid - px * 3;
        if (px < npix) {
            float s = olb[a];
            for (int e = 0; e < 256; ++e)
                s = fmaf(olw[a * 256 + e], (float)hb[((e >> 4) * 64 + px) * 24 + (e & 15)], s);
            out[olog_off(lv) + ((size_t)n * 3 + a) * HW + p0 + px] = s;
        }
    }
}

extern "C" void kernel_launch(void* const* d_in, const int* in_sizes, int n_in,
                              void* d_out, int out_size, void* d_ws, size_t ws_size,
                              hipStream_t stream)
{
    const float* feat[4] = {(const float*)d_in[0], (const float*)d_in[1],
                            (const float*)d_in[2], (const float*)d_in[3]};
    const float* pc1w = (const float*)d_in[4];  const float* pc1b = (const float*)d_in[5];
    const float* pc2w = (const float*)d_in[6];  const float* pc2b = (const float*)d_in[7];
    const float* oc1w = (const float*)d_in[8];  const float* oc1b = (const float*)d_in[9];
    const float* oc2w = (const float*)d_in[10]; const float* oc2b = (const float*)d_in[11];
    const float* rn1w = (const float*)d_in[12]; const float* rn1b = (const float*)d_in[13];
    const float* rn2w = (const float*)d_in[14]; const float* rn2b = (const float*)d_in[15];
    const float* plw  = (const float*)d_in[16]; const float* plb  = (const float*)d_in[17];
    const float* pdw  = (const float*)d_in[18]; const float* pdb  = (const float*)d_in[19];
    const float* olw  = (const float*)d_in[20]; const float* olb  = (const float*)d_in[21];
    const float* odw  = (const float*)d_in[22]; const float* odb  = (const float*)d_in[23];

    float* ws = (float*)d_ws;
    // bf16-interleaved activation buffers (each 6,963,200 bf16 = 3,481,600 fl)
    __bf16* bufA = (__bf16*)(ws);             // X16 -> H16p
    __bf16* bufB = (__bf16*)(ws + 3481600);   // Y16p -> H16o
    __bf16* bufC = (__bf16*)(ws + 6963200);   // Y16o
    __bf16* wt_pc1 = (__bf16*)(ws + 10444800);
    __bf16* wt_pc2 = wt_pc1 + 589824;
    __bf16* wt_oc1 = wt_pc1 + 2 * 589824;
    __bf16* wt_oc2 = wt_pc1 + 3 * 589824;
    __bf16* Wo16  = (__bf16*)(ws + 11624448);
    __bf16* rn216 = (__bf16*)(ws + 11657216);
    float* WpT    = ws + 11689984;
    float* scores = ws + 11755520;
    float* lv_sc  = ws + 11782720;
    int*   lv_ix  = (int*)(ws + 11782880);
    float* pf     = ws + 11783040;
    float* pp     = ws + 11793280;
    float* out    = (float*)d_out;

    // ---- prep ----
    hipLaunchKernelGGL(prep_wtap_k, dim3(36, 256), dim3(256), 0, stream,
                       pc1w, pc2w, oc1w, oc2w, wt_pc1, wt_pc2, wt_oc1, wt_oc2);
    hipLaunchKernelGGL(prep_rel_k, dim3(256), dim3(256), 0, stream,
                       rn1w, rn2w, WpT, Wo16, rn216);
    hipLaunchKernelGGL(feat2x16_k, dim3(54, 2, 32), dim3(256), 0, stream,
                       feat[0], feat[1], feat[2], feat[3], bufA);

    // ---- convs (batched all levels) ----
    hipLaunchKernelGGL(conv3x3_v2, dim3(54, 4, 4), dim3(256), 0, stream,
                       bufA, wt_pc1, wt_oc1, pc1b, oc1b, bufB, bufC);
    hipLaunchKernelGGL(conv3x3_v2, dim3(54, 4, 2), dim3(256), 0, stream,
                       bufB, wt_pc2, wt_pc2, pc2b, pc2b, bufA, bufA);
    hipLaunchKernelGGL(conv3x3_v2, dim3(54, 4, 2), dim3(256), 0, stream,
                       bufC, wt_oc2, wt_oc2, oc2b, oc2b, bufB, bufB);

    // ---- p-branch tail ----
    hipLaunchKernelGGL(p_heads_v2, dim3(54, 2), dim3(256), 0, stream,
                       bufA, plw, plb, pdw, pdb, out, scores);
    hipLaunchKernelGGL(topk_level_k, dim3(4, 2), dim3(256), 0, stream,
                       scores, lv_sc, lv_ix);
    hipLaunchKernelGGL(select_gather_v2, dim3(2), dim3(256), 0, stream,
                       lv_sc, lv_ix, bufA, pf);
    hipLaunchKernelGGL(pproj_k, dim3(40), dim3(256), 0, stream, pf, WpT, rn1b, pp);

    // ---- o-branch tail ----
    hipLaunchKernelGGL(o_del_v2, dim3(54, 2), dim3(256), 0, stream,
                       bufB, odw, odb, out);
    hipLaunchKernelGGL(orel_k, dim3(213, 2), dim3(256), 0, stream,
                       bufB, Wo16, rn216, pp, rn2b, olw, olb, out);
}

// Round 4
// 621.308 us; speedup vs baseline: 14.6061x; 1.0780x over previous
//
#include <hip/hip_runtime.h>
#include <cstdint>
#include <cstddef>

typedef __bf16 bf16x8 __attribute__((ext_vector_type(8)));
typedef float  f32x16 __attribute__((ext_vector_type(16)));

union U16 { bf16x8 v; uint4 q; };
union U8  { __bf16 h[4]; unsigned long long u; };

// level helpers (256-pixel tiles): tile counts 40,10,3,1 -> bounds 40,50,53,54
__device__ __forceinline__ int lvl256(int bx) {
    return (bx < 40) ? 0 : (bx < 50) ? 1 : (bx < 53) ? 2 : 3;
}
__device__ __forceinline__ int tbase256(int lv) {
    return (lv == 0) ? 0 : (lv == 1) ? 40 : (lv == 2) ? 50 : 53;
}
__device__ __forceinline__ size_t loffE(int lv) {   // bf16-element offset of level block
    return (lv == 0) ? 0 : (lv == 1) ? 5242880 : (lv == 2) ? 6553600 : 6881280;
}
__device__ __forceinline__ size_t plog_off(int lv) {
    return (lv == 0) ? 0 : (lv == 1) ? 61440 : (lv == 2) ? 76800 : 80640;
}
__device__ __forceinline__ size_t pdel_off(int lv) {
    return (lv == 0) ? 81600 : (lv == 1) ? 327360 : (lv == 2) ? 388800 : 404160;
}
__device__ __forceinline__ size_t olog_off(int lv) {
    return (lv == 0) ? 408000 : (lv == 1) ? 469440 : (lv == 2) ? 484800 : 488640;
}
__device__ __forceinline__ size_t odel_off(int lv) {
    return (lv == 0) ? 489600 : (lv == 1) ? 735360 : (lv == 2) ? 796800 : 812160;
}
__device__ __forceinline__ int soff_l(int lv) {
    return (lv == 0) ? 0 : (lv == 1) ? 20480 : (lv == 2) ? 25600 : 26880;
}

// ---------------- weight prep: fp32 [co][ci][3][3] -> bf16 [t][ci16][co][16] -
__global__ __launch_bounds__(256) void prep_wtap2_k(
    const float* w0, const float* w1, const float* w2, const float* w3,
    __bf16* d0, __bf16* d1, __bf16* d2, __bf16* d3)
{
    int t = blockIdx.x % 9, which = blockIdx.x / 9;
    int co = blockIdx.y, ci = threadIdx.x;
    const float* src = (which == 0) ? w0 : (which == 1) ? w1 : (which == 2) ? w2 : w3;
    __bf16* dst = (which == 0) ? d0 : (which == 1) ? d1 : (which == 2) ? d2 : d3;
    dst[((size_t)(t * 16 + (ci >> 4)) * 256 + co) * 16 + (ci & 15)] =
        (__bf16)src[(size_t)(co * 256 + ci) * 9 + t];
}

// ---------------- relnet weight prep + zero-row init ------------------------
__global__ __launch_bounds__(256) void prep_rel_k(
    const float* __restrict__ rn1w, const float* __restrict__ rn2w,
    float* __restrict__ WpT, __bf16* __restrict__ Wo16, __bf16* __restrict__ rn216,
    unsigned* __restrict__ zrow32)
{
    int d = blockIdx.x, c = threadIdx.x;
    WpT[c * 256 + d] = rn1w[(size_t)d * 512 + 256 + c];
    Wo16[((c >> 4) * 256 + d) * 16 + (c & 15)] = (__bf16)rn1w[(size_t)d * 512 + c];
    rn216[((c >> 4) * 256 + d) * 16 + (c & 15)] = (__bf16)rn2w[(size_t)d * 256 + c];
    if (d == 0 && c < 256) zrow32[c] = 0u;   // 1 KB zeros
}

// ---------------- feats fp32 planar -> bf16 interleaved [ch16][pixel][16] ----
__global__ __launch_bounds__(256) void feat2x16_k(
    const float* f0, const float* f1, const float* f2, const float* f3,
    __bf16* __restrict__ x16)
{
    int bx = blockIdx.x, n = blockIdx.y, z = blockIdx.z;
    int lv = lvl256(bx);
    int HW = 10240 >> (2 * lv);
    int p = (bx - tbase256(lv)) * 256 + threadIdx.x;
    if (p >= HW) return;
    const float* f = (lv == 0) ? f0 : (lv == 1) ? f1 : (lv == 2) ? f2 : f3;
    int ch = z >> 1, u = z & 1;
    const float* src = f + (size_t)n * 256 * HW + (size_t)(ch * 16 + u * 8) * HW + p;
    U16 v;
#pragma unroll
    for (int j = 0; j < 8; ++j) v.v[j] = (__bf16)src[(size_t)j * HW];
    *(uint4*)&x16[loffE(lv) + (size_t)n * HW * 256 + (((size_t)ch * HW + p) << 4) + (u << 3)] = v.q;
}

// ---------------- conv 3x3 SAME: zero-LDS, direct-from-global MFMA ----------
// grid: (54 tiles, 4 co-groups of 64, z = n + 2*branch). block 256 = 4 waves,
// each wave 64co x 64px (2x2 frags of 32x32x16). All frags loaded straight
// from L1/L2 as 1KB-contiguous global_load_dwordx4; OOB lanes -> zero row.
__global__ __launch_bounds__(256) void conv3x3_v3(
    const __bf16* __restrict__ in16,
    const __bf16* __restrict__ wt0, const __bf16* __restrict__ wt1,
    const float* __restrict__ b0p, const float* __restrict__ b1p,
    const __bf16* __restrict__ zrow,
    __bf16* __restrict__ out0, __bf16* __restrict__ out1)
{
    const int tid = threadIdx.x;
    const int zz = blockIdx.z;
    const int n = zz & 1, br = zz >> 1;
    const __bf16* wt = br ? wt1 : wt0;
    const float* bias = br ? b1p : b0p;
    __bf16* outp = br ? out1 : out0;

    const int bx = blockIdx.x;
    const int lv = lvl256(bx);
    const int lg2W = 7 - lv;
    const int W = 1 << lg2W, H = 80 >> lv;
    const int HW = 10240 >> (2 * lv);
    const size_t ioff = loffE(lv) + (size_t)n * HW * 256;
    const __bf16* inb = in16 + ioff;

    const int tile = bx - tbase256(lv);
    const int sp0 = tile << 8;
    const int npix = min(256, HW - sp0);

    const int w = tid >> 6, l64 = tid & 63;
    const int lane = l64 & 31, half = l64 >> 5;
    const int pix0 = (w << 6) + lane, pix1 = pix0 + 32;
    const int cobase = blockIdx.y << 6;

    // chunk-invariant per-tap byte offsets for both pixel slots (-1 = OOB)
    int boff0[9], boff1[9];
    {
        const int y0 = sp0 >> lg2W;
        const int py0 = pix0 >> lg2W, px0 = pix0 & (W - 1);
        const int py1 = pix1 >> lg2W, px1 = pix1 & (W - 1);
#pragma unroll
        for (int dy = 0; dy < 3; ++dy)
#pragma unroll
            for (int dx = 0; dx < 3; ++dx) {
                int t = dy * 3 + dx;
                int gy0 = y0 + py0 + dy - 1, gx0 = px0 + dx - 1;
                boff0[t] = ((unsigned)gy0 < (unsigned)H && (unsigned)gx0 < (unsigned)W)
                           ? (((gy0 << lg2W) + gx0) * 32 + half * 16) : -1;
                int gy1 = y0 + py1 + dy - 1, gx1 = px1 + dx - 1;
                boff1[t] = ((unsigned)gy1 < (unsigned)H && (unsigned)gx1 < (unsigned)W)
                           ? (((gy1 << lg2W) + gx1) * 32 + half * 16) : -1;
            }
    }
    const __bf16* zp = zrow + (half << 3);   // 16B of zeros per half

    f32x16 acc00 = {}, acc01 = {}, acc10 = {}, acc11 = {};

    for (int c16 = 0; c16 < 16; ++c16) {
        const char* curB = (const char*)inb + (size_t)c16 * HW * 32;
        const char* curA = (const char*)wt + ((size_t)c16 * 256 + cobase) * 32
                           + lane * 32 + half * 16;
#pragma unroll
        for (int t = 0; t < 9; ++t) {
            const char* ab = curA + (size_t)t * 131072;   // 16*256*16*2 B per tap
            bf16x8 a0 = *(const bf16x8*)ab;
            bf16x8 a1 = *(const bf16x8*)(ab + 1024);
            const __bf16* q0 = (boff0[t] >= 0) ? (const __bf16*)(curB + boff0[t]) : zp;
            const __bf16* q1 = (boff1[t] >= 0) ? (const __bf16*)(curB + boff1[t]) : zp;
            bf16x8 b0 = *(const bf16x8*)q0;
            bf16x8 b1 = *(const bf16x8*)q1;
            acc00 = __builtin_amdgcn_mfma_f32_32x32x16_bf16(a0, b0, acc00, 0, 0, 0);
            acc01 = __builtin_amdgcn_mfma_f32_32x32x16_bf16(a0, b1, acc01, 0, 0, 0);
            acc10 = __builtin_amdgcn_mfma_f32_32x32x16_bf16(a1, b0, acc10, 0, 0, 0);
            acc11 = __builtin_amdgcn_mfma_f32_32x32x16_bf16(a1, b1, acc11, 0, 0, 0);
        }
    }
    // epilogue: C/D col=lane (pixel), row=(reg&3)+8*(reg>>2)+4*half (co); bf16 pack
    const int pixg0 = sp0 + pix0, pixg1 = sp0 + pix1;
    const bool ok0 = (pix0 < npix), ok1 = (pix1 < npix);
#pragma unroll
    for (int b = 0; b < 2; ++b) {
        const f32x16& A0 = b ? acc10 : acc00;
        const f32x16& A1 = b ? acc11 : acc01;
#pragma unroll
        for (int q = 0; q < 4; ++q) {
            int co0 = cobase + b * 32 + q * 8 + half * 4;
            float4 bq = *(const float4*)&bias[co0];
            U8 v0, v1;
            v0.h[0] = (__bf16)fmaxf(A0[q * 4 + 0] + bq.x, 0.f);
            v0.h[1] = (__bf16)fmaxf(A0[q * 4 + 1] + bq.y, 0.f);
            v0.h[2] = (__bf16)fmaxf(A0[q * 4 + 2] + bq.z, 0.f);
            v0.h[3] = (__bf16)fmaxf(A0[q * 4 + 3] + bq.w, 0.f);
            v1.h[0] = (__bf16)fmaxf(A1[q * 4 + 0] + bq.x, 0.f);
            v1.h[1] = (__bf16)fmaxf(A1[q * 4 + 1] + bq.y, 0.f);
            v1.h[2] = (__bf16)fmaxf(A1[q * 4 + 2] + bq.z, 0.f);
            v1.h[3] = (__bf16)fmaxf(A1[q * 4 + 3] + bq.w, 0.f);
            size_t base = ioff + (((size_t)(co0 >> 4) * HW) << 4) + (co0 & 15);
            if (ok0) *(unsigned long long*)&outp[base + ((size_t)pixg0 << 4)] = v0.u;
            if (ok1) *(unsigned long long*)&outp[base + ((size_t)pixg1 << 4)] = v1.u;
        }
    }
}

// ---------------- p-branch 1x1 heads (batched levels) -----------------------
__global__ __launch_bounds__(256) void p_heads_v2(
    const __bf16* __restrict__ h16, const float* __restrict__ plw,
    const float* __restrict__ plb, const float* __restrict__ pdw,
    const float* __restrict__ pdb, float* __restrict__ out,
    float* __restrict__ scores)
{
    int bx = blockIdx.x, n = blockIdx.y;
    int lv = lvl256(bx);
    int HW = 10240 >> (2 * lv);
    int p = (bx - tbase256(lv)) * 256 + threadIdx.x;
    if (p >= HW) return;
    size_t ioff = loffE(lv) + (size_t)n * HW * 256;
    float acc[15];
#pragma unroll
    for (int a = 0; a < 15; ++a) acc[a] = 0.f;
    for (int ch = 0; ch < 16; ++ch) {
        size_t base = ioff + (((size_t)ch * HW + p) << 4);
        bf16x8 v0 = *(const bf16x8*)&h16[base];
        bf16x8 v1 = *(const bf16x8*)&h16[base + 8];
#pragma unroll
        for (int j = 0; j < 16; ++j) {
            float vv = (j < 8) ? (float)v0[j] : (float)v1[j - 8];
            int c = ch * 16 + j;
#pragma unroll
            for (int a = 0; a < 3; ++a)  acc[a]     = fmaf(plw[a * 256 + c], vv, acc[a]);
#pragma unroll
            for (int a = 0; a < 12; ++a) acc[3 + a] = fmaf(pdw[a * 256 + c], vv, acc[3 + a]);
        }
    }
    float sc = -INFINITY;
#pragma unroll
    for (int a = 0; a < 3; ++a) {
        float lg = acc[a] + plb[a];
        out[plog_off(lv) + ((size_t)n * 3 + a) * HW + p] = lg;
        sc = fmaxf(sc, lg);
    }
    scores[soff_l(lv) + (size_t)n * HW + p] = sc;
#pragma unroll
    for (int a = 0; a < 12; ++a)
        out[pdel_off(lv) + ((size_t)n * 12 + a) * HW + p] = acc[3 + a] + pdb[a];
}

// ---------------- o-branch 1x1 head o_del (batched levels) ------------------
__global__ __launch_bounds__(256) void o_del_v2(
    const __bf16* __restrict__ h16, const float* __restrict__ odw,
    const float* __restrict__ odb, float* __restrict__ out)
{
    int bx = blockIdx.x, n = blockIdx.y;
    int lv = lvl256(bx);
    int HW = 10240 >> (2 * lv);
    int p = (bx - tbase256(lv)) * 256 + threadIdx.x;
    if (p >= HW) return;
    size_t ioff = loffE(lv) + (size_t)n * HW * 256;
    float acc[12];
#pragma unroll
    for (int a = 0; a < 12; ++a) acc[a] = 0.f;
    for (int ch = 0; ch < 16; ++ch) {
        size_t base = ioff + (((size_t)ch * HW + p) << 4);
        bf16x8 v0 = *(const bf16x8*)&h16[base];
        bf16x8 v1 = *(const bf16x8*)&h16[base + 8];
#pragma unroll
        for (int j = 0; j < 16; ++j) {
            float vv = (j < 8) ? (float)v0[j] : (float)v1[j - 8];
            int c = ch * 16 + j;
#pragma unroll
            for (int a = 0; a < 12; ++a) acc[a] = fmaf(odw[a * 256 + c], vv, acc[a]);
        }
    }
#pragma unroll
    for (int a = 0; a < 12; ++a)
        out[odel_off(lv) + ((size_t)n * 12 + a) * HW + p] = acc[a] + odb[a];
}

// ---------------- per-level top-20 ------------------------------------------
__global__ __launch_bounds__(256) void topk_level_k(
    const float* __restrict__ scores, float* __restrict__ lv_sc,
    int* __restrict__ lv_ix)
{
    int l = blockIdx.x, n = blockIdx.y;
    int HW = 10240 >> (2 * l);
    int so = soff_l(l);
    __shared__ float sc[10240];
    __shared__ float rv[256];
    __shared__ int   ri[256];
    int tid = threadIdx.x;
    for (int i = tid; i < HW; i += 256) sc[i] = scores[so + (size_t)n * HW + i];
    __syncthreads();
    for (int r = 0; r < 20; ++r) {
        float bv = -INFINITY; int bi = 0x7fffffff;
        for (int i = tid; i < HW; i += 256) {
            float v = sc[i];
            if (v > bv || (v == bv && i < bi)) { bv = v; bi = i; }
        }
        rv[tid] = bv; ri[tid] = bi;
        __syncthreads();
        for (int off = 128; off > 0; off >>= 1) {
            if (tid < off) {
                float v2 = rv[tid + off]; int i2 = ri[tid + off];
                if (v2 > rv[tid] || (v2 == rv[tid] && i2 < ri[tid])) {
                    rv[tid] = v2; ri[tid] = i2;
                }
            }
            __syncthreads();
        }
        if (tid == 0) {
            int idx = (n * 4 + l) * 20 + r;
            lv_sc[idx] = rv[0];
            lv_ix[idx] = ri[0];
            sc[ri[0]] = -INFINITY;
        }
        __syncthreads();
    }
}

// ---------------- global top-20 of 80 + gather pf (bf16 hidden) -------------
__global__ __launch_bounds__(256) void select_gather_v2(
    const float* __restrict__ lv_sc, const int* __restrict__ lv_ix,
    const __bf16* __restrict__ h16, float* __restrict__ pf)
{
    int n = blockIdx.x;
    __shared__ float gsc[80];
    __shared__ int   gcell[80];
    __shared__ int   selL[20], selC[20];
    __shared__ float rv[256];
    __shared__ int   ri[256];
    int tid = threadIdx.x;
    if (tid < 80) {
        gsc[tid] = lv_sc[n * 80 + tid];
        gcell[tid] = lv_ix[n * 80 + tid];
    }
    __syncthreads();
    for (int r = 0; r < 20; ++r) {
        float bv = -INFINITY; int bi = 0x7fffffff;
        if (tid < 80) { bv = gsc[tid]; bi = tid; }
        rv[tid] = bv; ri[tid] = bi;
        __syncthreads();
        for (int off = 128; off > 0; off >>= 1) {
            if (tid < off) {
                float v2 = rv[tid + off]; int i2 = ri[tid + off];
                if (v2 > rv[tid] || (v2 == rv[tid] && i2 < ri[tid])) {
                    rv[tid] = v2; ri[tid] = i2;
                }
            }
            __syncthreads();
        }
        if (tid == 0) {
            int j = ri[0];
            selL[r] = j / 20;
            selC[r] = gcell[j];
            gsc[j] = -INFINITY;
        }
        __syncthreads();
    }
    for (int t = tid; t < 20 * 256; t += 256) {
        int k = t >> 8, c = t & 255;
        int l = selL[k], cell = selC[k];
        int HW = 10240 >> (2 * l);
        pf[((size_t)n * 20 + k) * 256 + c] =
            (float)h16[loffE(l) + (size_t)n * HW * 256 +
                       (((size_t)(c >> 4) * HW + cell) << 4) + (c & 15)];
    }
}

// ---------------- p_proj = pf @ Wp^T + rn1_b (fp32) -------------------------
__global__ __launch_bounds__(256) void pproj_k(
    const float* __restrict__ pf, const float* __restrict__ WpT,
    const float* __restrict__ rn1b, float* __restrict__ pp)
{
    int nk = blockIdx.x;
    int t = threadIdx.x;
    __shared__ float f[256];
    f[t] = pf[(size_t)nk * 256 + t];
    __syncthreads();
    float acc = rn1b[t];
    for (int c = 0; c < 256; ++c) acc = fmaf(f[c], WpT[c * 256 + t], acc);
    pp[(size_t)nk * 256 + t] = acc;
}

// ---------------- fused o_proj + hsum + rn2 + ol (MFMA) ---------------------
__global__ __launch_bounds__(256) void orel_k(
    const __bf16* __restrict__ H16o, const __bf16* __restrict__ Wo16,
    const __bf16* __restrict__ rn216, const float* __restrict__ pp,
    const float* __restrict__ rn2b, const float* __restrict__ olw,
    const float* __restrict__ olb, float* __restrict__ out)
{
    __shared__ __bf16 hb[16 * 64 * 24];   // [dch][px][16 + pad8] pitch 24
    __shared__ __bf16 pp16[5120];
    const int tid = threadIdx.x;
    const int n = blockIdx.y;
    int bx = blockIdx.x;
    int lv = (bx < 160) ? 0 : (bx < 200) ? 1 : (bx < 210) ? 2 : 3;
    int tb = (lv == 0) ? 0 : (lv == 1) ? 160 : (lv == 2) ? 200 : 210;
    int HW = 10240 >> (2 * lv);
    size_t yoff = loffE(lv) + (size_t)n * HW * 256;
    int p0 = (bx - tb) << 6;
    int npix = min(64, HW - p0);

    {
        const float* ps = pp + (size_t)n * 5120;
        for (int i = tid; i < 1280; i += 256) {
            float4 f = *(const float4*)&ps[i * 4];
            U8 v;
            v.h[0] = (__bf16)f.x; v.h[1] = (__bf16)f.y;
            v.h[2] = (__bf16)f.z; v.h[3] = (__bf16)f.w;
            *(unsigned long long*)&pp16[i * 4] = v.u;
        }
    }
    __syncthreads();

    const int w = tid >> 6, l64 = tid & 63;
    const int lane = l64 & 31, half = l64 >> 5;
    const int dbase = w << 6;

    f32x16 acc00 = {}, acc01 = {}, acc10 = {}, acc11 = {};
    for (int c16 = 0; c16 < 16; ++c16) {
        bf16x8 a0 = *(const bf16x8*)&Wo16[(((c16 << 8) + dbase + lane) << 4) + (half << 3)];
        bf16x8 a1 = *(const bf16x8*)&Wo16[(((c16 << 8) + dbase + 32 + lane) << 4) + (half << 3)];
        bf16x8 b0 = *(const bf16x8*)&H16o[yoff + (((size_t)c16 * HW + p0 + lane) << 4) + (half << 3)];
        bf16x8 b1 = *(const bf16x8*)&H16o[yoff + (((size_t)c16 * HW + p0 + 32 + lane) << 4) + (half << 3)];
        acc00 = __builtin_amdgcn_mfma_f32_32x32x16_bf16(a0, b0, acc00, 0, 0, 0);
        acc01 = __builtin_amdgcn_mfma_f32_32x32x16_bf16(a0, b1, acc01, 0, 0, 0);
        acc10 = __builtin_amdgcn_mfma_f32_32x32x16_bf16(a1, b0, acc10, 0, 0, 0);
        acc11 = __builtin_amdgcn_mfma_f32_32x32x16_bf16(a1, b1, acc11, 0, 0, 0);
    }
#pragma unroll
    for (int b = 0; b < 2; ++b) {
        const f32x16& A0 = b ? acc10 : acc00;
        const f32x16& A1 = b ? acc11 : acc01;
#pragma unroll
        for (int q = 0; q < 4; ++q) {
            int d0 = dbase + b * 32 + q * 8 + half * 4;
            float h0[4] = {0.f, 0.f, 0.f, 0.f}, h1[4] = {0.f, 0.f, 0.f, 0.f};
            for (int k = 0; k < 20; ++k) {
                U8 pk;
                pk.u = *(const unsigned long long*)&pp16[k * 256 + d0];
#pragma unroll
                for (int j = 0; j < 4; ++j) {
                    float pkv = (float)pk.h[j];
                    h0[j] += fmaxf(A0[q * 4 + j] + pkv, 0.f);
                    h1[j] += fmaxf(A1[q * 4 + j] + pkv, 0.f);
                }
            }
            U8 v0, v1;
#pragma unroll
            for (int j = 0; j < 4; ++j) { v0.h[j] = (__bf16)h0[j]; v1.h[j] = (__bf16)h1[j]; }
            *(unsigned long long*)&hb[((d0 >> 4) * 64 + lane) * 24 + (d0 & 15)] = v0.u;
            *(unsigned long long*)&hb[((d0 >> 4) * 64 + 32 + lane) * 24 + (d0 & 15)] = v1.u;
        }
    }
    __syncthreads();
    f32x16 e00 = {}, e01 = {}, e10 = {}, e11 = {};
    for (int d16 = 0; d16 < 16; ++d16) {
        bf16x8 a0 = *(const bf16x8*)&rn216[(((d16 << 8) + dbase + lane) << 4) + (half << 3)];
        bf16x8 a1 = *(const bf16x8*)&rn216[(((d16 << 8) + dbase + 32 + lane) << 4) + (half << 3)];
        bf16x8 b0 = *(const bf16x8*)&hb[(d16 * 64 + lane) * 24 + (half << 3)];
        bf16x8 b1 = *(const bf16x8*)&hb[(d16 * 64 + 32 + lane) * 24 + (half << 3)];
        e00 = __builtin_amdgcn_mfma_f32_32x32x16_bf16(a0, b0, e00, 0, 0, 0);
        e01 = __builtin_amdgcn_mfma_f32_32x32x16_bf16(a0, b1, e01, 0, 0, 0);
        e10 = __builtin_amdgcn_mfma_f32_32x32x16_bf16(a1, b0, e10, 0, 0, 0);
        e11 = __builtin_amdgcn_mfma_f32_32x32x16_bf16(a1, b1, e11, 0, 0, 0);
    }
    __syncthreads();
#pragma unroll
    for (int b = 0; b < 2; ++b) {
        const f32x16& A0 = b ? e10 : e00;
        const f32x16& A1 = b ? e11 : e01;
#pragma unroll
        for (int q = 0; q < 4; ++q) {
            int e0 = dbase + b * 32 + q * 8 + half * 4;
            float4 bb = *(const float4*)&rn2b[e0];
            U8 v0, v1;
            v0.h[0] = (__bf16)fmaxf(A0[q * 4 + 0] + bb.x, 0.f);
            v0.h[1] = (__bf16)fmaxf(A0[q * 4 + 1] + bb.y, 0.f);
            v0.h[2] = (__bf16)fmaxf(A0[q * 4 + 2] + bb.z, 0.f);
            v0.h[3] = (__bf16)fmaxf(A0[q * 4 + 3] + bb.w, 0.f);
            v1.h[0] = (__bf16)fmaxf(A1[q * 4 + 0] + bb.x, 0.f);
            v1.h[1] = (__bf16)fmaxf(A1[q * 4 + 1] + bb.y, 0.f);
            v1.h[2] = (__bf16)fmaxf(A1[q * 4 + 2] + bb.z, 0.f);
            v1.h[3] = (__bf16)fmaxf(A1[q * 4 + 3] + bb.w, 0.f);
            *(unsigned long long*)&hb[((e0 >> 4) * 64 + lane) * 24 + (e0 & 15)] = v0.u;
            *(unsigned long long*)&hb[((e0 >> 4) * 64 + 32 + lane) * 24 + (e0 & 15)] = v1.u;
        }
    }
    __syncthreads();
    if (tid < 192) {
        int px = tid / 3, a = tid - px * 3;
        if (px < npix) {
            float s = olb[a];
            for (int e = 0; e < 256; ++e)
                s = fmaf(olw[a * 256 + e], (float)hb[((e >> 4) * 64 + px) * 24 + (e & 15)], s);
            out[olog_off(lv) + ((size_t)n * 3 + a) * HW + p0 + px] = s;
        }
    }
}

extern "C" void kernel_launch(void* const* d_in, const int* in_sizes, int n_in,
                              void* d_out, int out_size, void* d_ws, size_t ws_size,
                              hipStream_t stream)
{
    const float* feat[4] = {(const float*)d_in[0], (const float*)d_in[1],
                            (const float*)d_in[2], (const float*)d_in[3]};
    const float* pc1w = (const float*)d_in[4];  const float* pc1b = (const float*)d_in[5];
    const float* pc2w = (const float*)d_in[6];  const float* pc2b = (const float*)d_in[7];
    const float* oc1w = (const float*)d_in[8];  const float* oc1b = (const float*)d_in[9];
    const float* oc2w = (const float*)d_in[10]; const float* oc2b = (const float*)d_in[11];
    const float* rn1w = (const float*)d_in[12]; const float* rn1b = (const float*)d_in[13];
    const float* rn2w = (const float*)d_in[14]; const float* rn2b = (const float*)d_in[15];
    const float* plw  = (const float*)d_in[16]; const float* plb  = (const float*)d_in[17];
    const float* pdw  = (const float*)d_in[18]; const float* pdb  = (const float*)d_in[19];
    const float* olw  = (const float*)d_in[20]; const float* olb  = (const float*)d_in[21];
    const float* odw  = (const float*)d_in[22]; const float* odb  = (const float*)d_in[23];

    float* ws = (float*)d_ws;
    __bf16* bufA = (__bf16*)(ws);             // X16 -> H16p
    __bf16* bufB = (__bf16*)(ws + 3481600);   // Y16p -> H16o
    __bf16* bufC = (__bf16*)(ws + 6963200);   // Y16o
    __bf16* wt_pc1 = (__bf16*)(ws + 10444800);
    __bf16* wt_pc2 = wt_pc1 + 589824;
    __bf16* wt_oc1 = wt_pc1 + 2 * 589824;
    __bf16* wt_oc2 = wt_pc1 + 3 * 589824;
    __bf16* Wo16  = (__bf16*)(ws + 11624448);
    __bf16* rn216 = (__bf16*)(ws + 11657216);
    float* WpT    = ws + 11689984;
    float* scores = ws + 11755520;
    float* lv_sc  = ws + 11782720;
    int*   lv_ix  = (int*)(ws + 11782880);
    float* pf     = ws + 11783040;
    float* pp     = ws + 11793280;
    __bf16* zrow  = (__bf16*)(ws + 11803520);   // 512 bf16 zeros
    float* out    = (float*)d_out;

    // ---- prep ----
    hipLaunchKernelGGL(prep_wtap2_k, dim3(36, 256), dim3(256), 0, stream,
                       pc1w, pc2w, oc1w, oc2w, wt_pc1, wt_pc2, wt_oc1, wt_oc2);
    hipLaunchKernelGGL(prep_rel_k, dim3(256), dim3(256), 0, stream,
                       rn1w, rn2w, WpT, Wo16, rn216, (unsigned*)zrow);
    hipLaunchKernelGGL(feat2x16_k, dim3(54, 2, 32), dim3(256), 0, stream,
                       feat[0], feat[1], feat[2], feat[3], bufA);

    // ---- convs (batched all levels, zero-LDS direct MFMA) ----
    hipLaunchKernelGGL(conv3x3_v3, dim3(54, 4, 4), dim3(256), 0, stream,
                       bufA, wt_pc1, wt_oc1, pc1b, oc1b, zrow, bufB, bufC);
    hipLaunchKernelGGL(conv3x3_v3, dim3(54, 4, 2), dim3(256), 0, stream,
                       bufB, wt_pc2, wt_pc2, pc2b, pc2b, zrow, bufA, bufA);
    hipLaunchKernelGGL(conv3x3_v3, dim3(54, 4, 2), dim3(256), 0, stream,
                       bufC, wt_oc2, wt_oc2, oc2b, oc2b, zrow, bufB, bufB);

    // ---- p-branch tail ----
    hipLaunchKernelGGL(p_heads_v2, dim3(54, 2), dim3(256), 0, stream,
                       bufA, plw, plb, pdw, pdb, out, scores);
    hipLaunchKernelGGL(topk_level_k, dim3(4, 2), dim3(256), 0, stream,
                       scores, lv_sc, lv_ix);
    hipLaunchKernelGGL(select_gather_v2, dim3(2), dim3(256), 0, stream,
                       lv_sc, lv_ix, bufA, pf);
    hipLaunchKernelGGL(pproj_k, dim3(40), dim3(256), 0, stream, pf, WpT, rn1b, pp);

    // ---- o-branch tail ----
    hipLaunchKernelGGL(o_del_v2, dim3(54, 2), dim3(256), 0, stream,
                       bufB, odw, odb, out);
    hipLaunchKernelGGL(orel_k, dim3(213, 2), dim3(256), 0, stream,
                       bufB, Wo16, rn216, pp, rn2b, olw, olb, out);
}